// Round 28
// baseline (137.192 us; speedup 1.0000x reference)
//
#include <hip/hip_runtime.h>
#include <hip/hip_bf16.h>
#include <math.h>

#define EPS 1e-8f

typedef __attribute__((ext_vector_type(8))) short short8v;
typedef __attribute__((ext_vector_type(4))) float f32x4;

// ---------- helpers ----------
__device__ __forceinline__ unsigned fenc(float f) {
    unsigned u = __float_as_uint(f);
    return (u & 0x80000000u) ? ~u : (u | 0x80000000u);
}
__device__ __forceinline__ float fdec(unsigned e) {
    unsigned u = (e & 0x80000000u) ? (e & 0x7FFFFFFFu) : ~e;
    return __uint_as_float(u);
}
__device__ __forceinline__ unsigned short f2bf(float f) {   // RNE f32 -> bf16
    unsigned u = __float_as_uint(f);
    u += 0x7FFFu + ((u >> 16) & 1u);
    return (unsigned short)(u >> 16);
}

__device__ __forceinline__ float block_sum(float v, float* red) {
    red[threadIdx.x] = v;
    __syncthreads();
    for (int k = 128; k > 0; k >>= 1) {
        if (threadIdx.x < k) red[threadIdx.x] += red[threadIdx.x + k];
        __syncthreads();
    }
    float r = red[0];
    __syncthreads();
    return r;
}
__device__ __forceinline__ float block_max(float v, float* red) {
    red[threadIdx.x] = v;
    __syncthreads();
    for (int k = 128; k > 0; k >>= 1) {
        if (threadIdx.x < k) red[threadIdx.x] = fmaxf(red[threadIdx.x], red[threadIdx.x + k]);
        __syncthreads();
    }
    float r = red[0];
    __syncthreads();
    return r;
}

// ---------- kernels ----------
// FUSED prepass: blocks [0,64) = target histogram;
// blocks [64, 64+B/16) = per-row 1/max(||f||,eps)  (4 rows per wave, 16KB in flight);
// blocks [64+B/16, 64+B/16+B/8) = per-row logsumexp(logits) (2 rows per wave).
__global__ __launch_bounds__(256) void k_pre(const int* tgt, int* gh,
                                             const float* feat, float* fnorminv,
                                             const float* logits, float* lse,
                                             int B, int D, int C2) {
    __shared__ int lh[1024];
    int t = threadIdx.x;
    int bid = blockIdx.x;
    if (bid < 64) {
        int g = bid;
        lh[t] = 0; lh[t + 256] = 0; lh[t + 512] = 0; lh[t + 768] = 0;
        __syncthreads();
        int i = g * 256 + t;
        if (i < B) atomicAdd(&lh[tgt[i]], 1);
        __syncthreads();
        int* dst = gh + g * 1024;
        dst[t] = lh[t]; dst[t + 256] = lh[t + 256];
        dst[t + 512] = lh[t + 512]; dst[t + 768] = lh[t + 768];
        return;
    }
    int wid = t >> 6, lane = t & 63;
    int nfb = B / 16;                  // 1024 fnorm blocks (16 rows each)
    if (bid < 64 + nfb) {
        // 4 rows per wave: 16 independent float4 loads in flight
        int r0 = (bid - 64) * 16 + wid * 4;
        const float4* fa = (const float4*)(feat + (long)r0 * D);
        const float4* fb = (const float4*)(feat + (long)(r0 + 1) * D);
        const float4* fc = (const float4*)(feat + (long)(r0 + 2) * D);
        const float4* fd = (const float4*)(feat + (long)(r0 + 3) * D);
        float s0 = 0.f, s1 = 0.f, s2 = 0.f, s3 = 0.f;
#pragma unroll
        for (int k = 0; k < 4; k++) {
            float4 a = fa[lane + 64 * k];
            float4 b = fb[lane + 64 * k];
            float4 c = fc[lane + 64 * k];
            float4 d = fd[lane + 64 * k];
            s0 += a.x * a.x + a.y * a.y + a.z * a.z + a.w * a.w;
            s1 += b.x * b.x + b.y * b.y + b.z * b.z + b.w * b.w;
            s2 += c.x * c.x + c.y * c.y + c.z * c.z + c.w * c.w;
            s3 += d.x * d.x + d.y * d.y + d.z * d.z + d.w * d.w;
        }
#pragma unroll
        for (int o = 32; o > 0; o >>= 1) {
            s0 += __shfl_xor(s0, o);
            s1 += __shfl_xor(s1, o);
            s2 += __shfl_xor(s2, o);
            s3 += __shfl_xor(s3, o);
        }
        if (lane == 0) {
            fnorminv[r0]     = 1.f / fmaxf(sqrtf(s0), EPS);
            fnorminv[r0 + 1] = 1.f / fmaxf(sqrtf(s1), EPS);
            fnorminv[r0 + 2] = 1.f / fmaxf(sqrtf(s2), EPS);
            fnorminv[r0 + 3] = 1.f / fmaxf(sqrtf(s3), EPS);
        }
        return;
    }
    // lse path: 2 rows per wave (8KB in flight)
    int r0 = (bid - 64 - nfb) * 8 + wid * 2;
    const float4* la = (const float4*)(logits + (long)r0 * C2);
    const float4* lb = (const float4*)(logits + (long)(r0 + 1) * C2);
    int Q = C2 >> 2;    // 250
    float ta[16], tb[16];
    float ma = -INFINITY, mb = -INFINITY;
#pragma unroll
    for (int k = 0; k < 4; k++) {
        int j = lane + 64 * k;
        if (j < Q) {
            float4 va = la[j];
            float4 vb = lb[j];
            ta[4 * k] = va.x; ta[4 * k + 1] = va.y; ta[4 * k + 2] = va.z; ta[4 * k + 3] = va.w;
            tb[4 * k] = vb.x; tb[4 * k + 1] = vb.y; tb[4 * k + 2] = vb.z; tb[4 * k + 3] = vb.w;
            ma = fmaxf(ma, fmaxf(fmaxf(va.x, va.y), fmaxf(va.z, va.w)));
            mb = fmaxf(mb, fmaxf(fmaxf(vb.x, vb.y), fmaxf(vb.z, vb.w)));
        } else {
#pragma unroll
            for (int r = 0; r < 4; r++) { ta[4 * k + r] = -INFINITY; tb[4 * k + r] = -INFINITY; }
        }
    }
#pragma unroll
    for (int o = 32; o > 0; o >>= 1) {
        ma = fmaxf(ma, __shfl_xor(ma, o));
        mb = fmaxf(mb, __shfl_xor(mb, o));
    }
    float sa = 0.f, sb = 0.f;
#pragma unroll
    for (int i = 0; i < 16; i++) {
        if (ta[i] != -INFINITY) sa += __expf(ta[i] - ma);
        if (tb[i] != -INFINITY) sb += __expf(tb[i] - mb);
    }
#pragma unroll
    for (int o = 32; o > 0; o >>= 1) {
        sa += __shfl_xor(sa, o);
        sb += __shfl_xor(sb, o);
    }
    if (lane == 0) {
        lse[r0]     = ma + __logf(sa);
        lse[r0 + 1] = mb + __logf(sb);
    }
}

__global__ void k_bases(int* gh, int* counts, int* offsets, unsigned* minmax, int G, int C) {
    __shared__ int buf[1024];
    int c = threadIdx.x;
    if (c == 0) { minmax[0] = 0xFFFFFFFFu; minmax[1] = 0u; }
    int run = 0;
#pragma unroll 16
    for (int g = 0; g < G; g++) {
        int v = gh[g * 1024 + c];
        gh[g * 1024 + c] = run;
        run += v;
    }
    if (c < C) counts[c] = run;
    int v0 = (c < C) ? run : 0;
    buf[c] = v0;
    __syncthreads();
    for (int off = 1; off < 1024; off <<= 1) {
        int v = (c >= off) ? buf[c - off] : 0;
        __syncthreads();
        buf[c] += v;
        __syncthreads();
    }
    if (c < C) offsets[c] = buf[c] - v0;
}

__global__ void k_rank_scatter(const int* tgt, const int* offsets, const int* gh,
                               int* idx, int B) {
    __shared__ int lt[256];
    int g = blockIdx.x, t = threadIdx.x;
    int i = g * 256 + t;
    int my = (i < B) ? tgt[i] : -1;
    lt[t] = my;
    __syncthreads();
    if (i < B) {
        int rank = 0;
        for (int j = 0; j < t; j++) rank += (lt[j] == my);
        idx[offsets[my] + gh[g * 1024 + my] + rank] = i;
    }
}

// FUSED table build: blocks [0,C) -> feature table + norms + g = sum of normalized
// rows; blocks [C,2C) -> logit table. Register idx + __shfl broadcast; deterministic.
__global__ __launch_bounds__(256) void k_tables(const float* feat, const float* finit,
                                                const float* logits, const float* linit,
                                                const int* counts, const int* offsets,
                                                const int* idx, const float* fnorminv,
                                                float* ftab, float* ltab, float* norms,
                                                float* gsum,
                                                int C, int D, int C2) {
    __shared__ float red[256];
    int t = threadIdx.x;
    int lane = t & 63;
    if ((int)blockIdx.x < C) {
        int c = blockIdx.x;
        int n = counts[c];
        float o0, o1, o2, o3;
        float4 acc2 = {0.f, 0.f, 0.f, 0.f};
        if (n == 0) {
            float4 v = ((const float4*)(finit + (long)c * D))[t];
            o0 = v.x; o1 = v.y; o2 = v.z; o3 = v.w;
        } else {
            const float4* base4 = (const float4*)feat;
            int rowq = D >> 2;
            int o = offsets[c];
            float4 acc = {0.f, 0.f, 0.f, 0.f};
            for (int base = 0; base < n; base += 64) {
                int m = min(64, n - base);
                int lid = idx[o + base + min(lane, m - 1)];
                float fvl = fnorminv[lid];
                int m4 = m & ~3;
                int j = 0;
                for (; j < m4; j += 4) {
                    int i0 = __shfl(lid, j);
                    int i1 = __shfl(lid, j + 1);
                    int i2 = __shfl(lid, j + 2);
                    int i3 = __shfl(lid, j + 3);
                    float f0 = __shfl(fvl, j);
                    float f1 = __shfl(fvl, j + 1);
                    float f2 = __shfl(fvl, j + 2);
                    float f3 = __shfl(fvl, j + 3);
                    float4 v0 = base4[(long)i0 * rowq + t];
                    float4 v1 = base4[(long)i1 * rowq + t];
                    float4 v2 = base4[(long)i2 * rowq + t];
                    float4 v3 = base4[(long)i3 * rowq + t];
                    acc.x += v0.x; acc.y += v0.y; acc.z += v0.z; acc.w += v0.w;
                    acc2.x += v0.x * f0; acc2.y += v0.y * f0; acc2.z += v0.z * f0; acc2.w += v0.w * f0;
                    acc.x += v1.x; acc.y += v1.y; acc.z += v1.z; acc.w += v1.w;
                    acc2.x += v1.x * f1; acc2.y += v1.y * f1; acc2.z += v1.z * f1; acc2.w += v1.w * f1;
                    acc.x += v2.x; acc.y += v2.y; acc.z += v2.z; acc.w += v2.w;
                    acc2.x += v2.x * f2; acc2.y += v2.y * f2; acc2.z += v2.z * f2; acc2.w += v2.w * f2;
                    acc.x += v3.x; acc.y += v3.y; acc.z += v3.z; acc.w += v3.w;
                    acc2.x += v3.x * f3; acc2.y += v3.y * f3; acc2.z += v3.z * f3; acc2.w += v3.w * f3;
                }
                for (; j < m; j++) {
                    int i0 = __shfl(lid, j);
                    float f0 = __shfl(fvl, j);
                    float4 v0 = base4[(long)i0 * rowq + t];
                    acc.x += v0.x; acc.y += v0.y; acc.z += v0.z; acc.w += v0.w;
                    acc2.x += v0.x * f0; acc2.y += v0.y * f0; acc2.z += v0.z * f0; acc2.w += v0.w * f0;
                }
            }
            float inv = 1.0f / (float)n;
            o0 = acc.x * inv; o1 = acc.y * inv; o2 = acc.z * inv; o3 = acc.w * inv;
        }
        float* dst = ftab + (long)c * D + t * 4;
        dst[0] = o0; dst[1] = o1; dst[2] = o2; dst[3] = o3;
        if (n > 0) ((float4*)(gsum + (long)c * D))[t] = acc2;
        float ss = o0 * o0 + o1 * o1 + o2 * o2 + o3 * o3;
        ss = block_sum(ss, red);
        if (t == 0) norms[c] = sqrtf(ss);
    } else {
        int c = blockIdx.x - C;
        int n = counts[c];
        int nv = C2 >> 2;                           // 250
        if (n == 0) {
            for (int d = t; d < C2; d += 256) ltab[(long)c * C2 + d] = linit[(long)c * C2 + d];
            return;
        }
        int tc = min(t, nv - 1);
        int o = offsets[c];
        float4 acc = {0.f, 0.f, 0.f, 0.f};
        for (int base = 0; base < n; base += 64) {
            int m = min(64, n - base);
            int lid = idx[o + base + min(lane, m - 1)];
            int m4 = m & ~3;
            int j = 0;
            for (; j < m4; j += 4) {
                int i0 = __shfl(lid, j);
                int i1 = __shfl(lid, j + 1);
                int i2 = __shfl(lid, j + 2);
                int i3 = __shfl(lid, j + 3);
                float4 v0 = *(const float4*)(logits + (long)i0 * C2 + tc * 4);
                float4 v1 = *(const float4*)(logits + (long)i1 * C2 + tc * 4);
                float4 v2 = *(const float4*)(logits + (long)i2 * C2 + tc * 4);
                float4 v3 = *(const float4*)(logits + (long)i3 * C2 + tc * 4);
                acc.x += v0.x; acc.y += v0.y; acc.z += v0.z; acc.w += v0.w;
                acc.x += v1.x; acc.y += v1.y; acc.z += v1.z; acc.w += v1.w;
                acc.x += v2.x; acc.y += v2.y; acc.z += v2.z; acc.w += v2.w;
                acc.x += v3.x; acc.y += v3.y; acc.z += v3.z; acc.w += v3.w;
            }
            for (; j < m; j++) {
                int i0 = __shfl(lid, j);
                float4 v0 = *(const float4*)(logits + (long)i0 * C2 + tc * 4);
                acc.x += v0.x; acc.y += v0.y; acc.z += v0.z; acc.w += v0.w;
            }
        }
        if (t < nv) {
            float inv = 1.0f / (float)n;
            float* dst = ltab + (long)c * C2 + t * 4;
            dst[0] = acc.x * inv;
            dst[1] = acc.y * inv;
            dst[2] = acc.z * inv;
            dst[3] = acc.w * inv;
        }
    }
}

// Triangular raw-dot GEMM via bf16 MFMA: one block per upper-tri 64x64 tile.
__global__ __launch_bounds__(1024) void k_gemm(const float* A, float* S,
                                               int C, int D, int NT) {
    __shared__ __align__(16) unsigned short As[2][64][40];
    __shared__ __align__(16) unsigned short Bs[2][64][40];
    __shared__ __align__(16) float racc[64 * 68];
    int t = threadIdx.x;

    int q = blockIdx.x, ti = 0;
    while (q >= NT - ti) { q -= NT - ti; ti++; }
    int tj = ti + q;
    int rb = ti * 64, cb = tj * 64;

    int srow = t >> 4;
    int skq = (t & 15) * 2;
    int ga = rb + srow, gb = cb + srow;
    bool okA = ga < C, okB = gb < C;
    const float* arow = A + (long)ga * D;
    const float* brow = A + (long)gb * D;

    int w = t >> 6, wr = w >> 2, wc = w & 3;
    int l = t & 63, fr = l & 15, fb = l >> 4;
    int arl = wr * 16 + fr, brl = wc * 16 + fr, koff = fb * 8;

    {
        float2 z2 = {0.f, 0.f};
        float2 pa = okA ? *(const float2*)(arow + skq) : z2;
        float2 pb = okB ? *(const float2*)(brow + skq) : z2;
        As[0][srow][skq] = f2bf(pa.x); As[0][srow][skq + 1] = f2bf(pa.y);
        Bs[0][srow][skq] = f2bf(pb.x); Bs[0][srow][skq + 1] = f2bf(pb.y);
    }
    __syncthreads();

    f32x4 acc = {0.f, 0.f, 0.f, 0.f};
    int nsteps = D >> 5;               // 32
    for (int step = 0; step < nsteps; step++) {
        int cur = step & 1;
        float2 pa, pb;
        if (step < nsteps - 1) {
            int k0n = (step + 1) * 32;
            float2 z2 = {0.f, 0.f};
            pa = okA ? *(const float2*)(arow + k0n + skq) : z2;
            pb = okB ? *(const float2*)(brow + k0n + skq) : z2;
        }
        short8v af = *reinterpret_cast<const short8v*>(&As[cur][arl][koff]);
        short8v bf = *reinterpret_cast<const short8v*>(&Bs[cur][brl][koff]);
        acc = __builtin_amdgcn_mfma_f32_16x16x32_bf16(af, bf, acc, 0, 0, 0);
        if (step < nsteps - 1) {
            int nb = cur ^ 1;
            As[nb][srow][skq] = f2bf(pa.x); As[nb][srow][skq + 1] = f2bf(pa.y);
            Bs[nb][srow][skq] = f2bf(pb.x); Bs[nb][srow][skq + 1] = f2bf(pb.y);
        }
        __syncthreads();
    }

#pragma unroll
    for (int r = 0; r < 4; r++)
        racc[(wr * 16 + fb * 4 + r) * 68 + wc * 16 + fr] = acc[r];
    __syncthreads();

    int r0 = t >> 4;
    int cbl = (t & 15) * 4;
    int gr = rb + r0;
    bool edge = (tj == NT - 1);
    if (gr < C) {
        float4 v4 = *reinterpret_cast<const float4*>(&racc[r0 * 68 + cbl]);
        float v[4] = {v4.x, v4.y, v4.z, v4.w};
        float* dst = S + (long)gr * C + cb + cbl;
        if (!edge) {
            *reinterpret_cast<float2*>(dst) = make_float2(v[0], v[1]);
            *reinterpret_cast<float2*>(dst + 2) = make_float2(v[2], v[3]);
        } else {
#pragma unroll
            for (int m = 0; m < 4; m++)
                if (cb + cbl + m < C) dst[m] = v[m];
        }
    }
    if (ti != tj) {
        int cc0 = cb + r0;
        if (cc0 < C) {
            float wv[4];
#pragma unroll
            for (int m = 0; m < 4; m++) wv[m] = racc[(cbl + m) * 68 + r0];
            float* dst = S + (long)cc0 * C + rb + cbl;
            *reinterpret_cast<float2*>(dst) = make_float2(wv[0], wv[1]);
            *reinterpret_cast<float2*>(dst + 2) = make_float2(wv[2], wv[3]);
        }
    }
}

// per-row: best/argmax (excl diag) of cos values + global min/max (incl diag).
__global__ void k_rowmax(const float* S, const float* norms, unsigned* minmax,
                         float* simraw, int* simcls, int C) {
    __shared__ float invn[1024];
    __shared__ float rv[256], rmn[256], rmx[256];
    __shared__ int ri[256];
    int c = blockIdx.x, t = threadIdx.x;
    for (int j = t; j < C; j += 256) invn[j] = 1.f / norms[j];
    __syncthreads();
    float inc = invn[c];
    float best = -INFINITY, lmin = INFINITY, lmax = -INFINITY;
    int bi = 0x7FFFFFFF;
    long rowo = (long)c * C;
    for (int j = t; j < C; j += 256) {
        float v = S[rowo + j] * inc * invn[j];
        lmin = fminf(lmin, v);
        lmax = fmaxf(lmax, v);
        if (j != c && v > best) { best = v; bi = j; }
    }
    rv[t] = best; ri[t] = bi; rmn[t] = lmin; rmx[t] = lmax;
    __syncthreads();
    for (int k = 128; k > 0; k >>= 1) {
        if (t < k) {
            if (rv[t + k] > rv[t] || (rv[t + k] == rv[t] && ri[t + k] < ri[t])) {
                rv[t] = rv[t + k];
                ri[t] = ri[t + k];
            }
            rmn[t] = fminf(rmn[t], rmn[t + k]);
            rmx[t] = fmaxf(rmx[t], rmx[t + k]);
        }
        __syncthreads();
    }
    if (t == 0) {
        simraw[c] = rv[0];
        simcls[c] = ri[0];
        atomicMin(&minmax[0], fenc(rmn[0]));
        atomicMax(&minmax[1], fenc(rmx[0]));
    }
}

// Per-class losses via factored identities:
//  cpf[c] = n_c - dot(g_c,u_c)/max(|u_c|,eps) + sv_c*dot(g_c,v_c)/max(|v_c|,eps)
//  cpk[c] = LSE_c - n_c*lse(ltab_c)
__global__ __launch_bounds__(256) void k_closs(const float* gsum, const float* ftab,
                                               const float* norms, const int* counts,
                                               const int* offsets, const int* idx,
                                               const float* lse, const float* ltab,
                                               const unsigned* minmax, const float* simraw,
                                               const int* simcls,
                                               float* cpf, float* cpk,
                                               int C, int D, int C2) {
    __shared__ float red[256];
    int c = blockIdx.x, t = threadIdx.x;
    int n = counts[c];
    if (n == 0) {
        if (t == 0) { cpf[c] = 0.f; cpk[c] = 0.f; }
        return;
    }
    int sc = simcls[c];
    float4 g4 = ((const float4*)(gsum + (long)c * D))[t];
    const float* u = ftab + (long)c * D + t * 4;
    const float* v = ftab + (long)sc * D + t * 4;
    float d1 = g4.x * u[0] + g4.y * u[1] + g4.z * u[2] + g4.w * u[3];
    float d2 = g4.x * v[0] + g4.y * v[1] + g4.z * v[2] + g4.w * v[3];
    d1 = block_sum(d1, red);
    d2 = block_sum(d2, red);
    float ta[4];
    float lm = -INFINITY;
#pragma unroll
    for (int k = 0; k < 4; k++) {
        int j = t + k * 256;
        if (j < C2) { ta[k] = ltab[(long)c * C2 + j]; lm = fmaxf(lm, ta[k]); }
        else ta[k] = -INFINITY;
    }
    lm = block_max(lm, red);
    float se = 0.f;
#pragma unroll
    for (int k = 0; k < 4; k++)
        if (ta[k] != -INFINITY) se += __expf(ta[k] - lm);
    se = block_sum(se, red);
    float ls = 0.f;
    int o = offsets[c];
    for (int i = t; i < n; i += 256) ls += lse[idx[o + i]];
    ls = block_sum(ls, red);
    if (t == 0) {
        float cmin = fdec(minmax[0]);
        float cmax = fdec(minmax[1]);
        float sv = (simraw[c] - cmin) / (cmax - cmin);
        float nu = fmaxf(norms[c], EPS);
        float nv = fmaxf(norms[sc], EPS);
        cpf[c] = (float)n - d1 / nu + sv * d2 / nv;
        cpk[c] = ls - (float)n * (lm + __logf(se));
    }
}

__global__ void k_final(const float* cpf, const float* cpk, float* out, int C) {
    __shared__ float red[256];
    float a = 0.f;
    for (int i = threadIdx.x; i < C; i += 256) a += cpf[i];
    a = block_sum(a, red);
    float b = 0.f;
    for (int i = threadIdx.x; i < C; i += 256) b += cpk[i];
    b = block_sum(b, red);
    if (threadIdx.x == 0) {
        out[0] = a;
        out[1] = b;
    }
}

extern "C" void kernel_launch(void* const* d_in, const int* in_sizes, int n_in,
                              void* d_out, int out_size, void* d_ws, size_t ws_size,
                              hipStream_t stream) {
    const float* feature = (const float*)d_in[0];
    const float* logits  = (const float*)d_in[1];
    const int*   targets = (const int*)d_in[2];
    const float* finit   = (const float*)d_in[3];
    const float* linit   = (const float*)d_in[4];

    const int B = in_sizes[2];                 // 16384
    const int D = in_sizes[0] / B;             // 1024
    const int C = in_sizes[3] / D;             // 1000

    float* out = (float*)d_out;
    float* ftab = out + 2;                     // [C, D]
    float* ltab = out + 2 + (long)C * D;       // [C, C]

    const int G = 64;                          // histogram groups
    const int NT = (C + 63) / 64;              // 16 tiles per dim
    const int NTRI = NT * (NT + 1) / 2;        // 136 triangular tiles

    char* ws = (char*)d_ws;
    int*      counts   = (int*)(ws + 0);          // 4KB
    int*      offsets  = (int*)(ws + 4096);       // 4KB
    int*      idx      = (int*)(ws + 12288);      // 64KB
    float*    norms    = (float*)(ws + 77824);    // 4KB
    float*    simraw   = (float*)(ws + 81920);    // 4KB
    int*      simcls   = (int*)(ws + 86016);      // 4KB
    unsigned* minmax   = (unsigned*)(ws + 90112); // 8B
    float*    cpf      = (float*)(ws + 90368);    // 4KB
    float*    cpk      = (float*)(ws + 94464);    // 4KB
    float*    fnorminv = (float*)(ws + 98560);    // 64KB
    float*    lse      = (float*)(ws + 164096);   // 64KB
    float*    Sws      = (float*)(ws + 262144);   // C*C floats = 4MB
    float*    gsum     = (float*)(ws + 262144 + (size_t)C * C * sizeof(float)); // C*D

    float* S = Sws;                            // ws_size >= 12.25MB proven (round 12)

    // gh scratch lives in the (not-yet-written) ltab output region
    int* gh = (int*)ltab;

    // prepass: histogram + per-row 1/|f| (4 rows/wave) + per-row lse (2 rows/wave)
    k_pre<<<64 + B / 16 + B / 8, 256, 0, stream>>>(targets, gh, feature, fnorminv,
                                                   logits, lse, B, D, C);
    k_bases<<<1, 1024, 0, stream>>>(gh, counts, offsets, minmax, G, C);
    k_rank_scatter<<<G, 256, 0, stream>>>(targets, offsets, gh, idx, B);

    // both gathers in one dispatch; feature path also accumulates g = sum(f/|f|)
    k_tables<<<2 * C, 256, 0, stream>>>(feature, finit, logits, linit,
                                        counts, offsets, idx, fnorminv,
                                        ftab, ltab, norms, gsum, C, D, C);

    k_gemm<<<NTRI, 1024, 0, stream>>>(ftab, S, C, D, NT);
    k_rowmax<<<C, 256, 0, stream>>>(S, norms, minmax, simraw, simcls, C);
    k_closs<<<C, 256, 0, stream>>>(gsum, ftab, norms, counts, offsets, idx,
                                   lse, ltab, minmax, simraw, simcls, cpf, cpk, C, D, C);
    k_final<<<1, 256, 0, stream>>>(cpf, cpk, out, C);
}

// Round 29
// 133.903 us; speedup vs baseline: 1.0246x; 1.0246x over previous
//
#include <hip/hip_runtime.h>
#include <hip/hip_bf16.h>
#include <math.h>

#define EPS 1e-8f

typedef __attribute__((ext_vector_type(8))) short short8v;
typedef __attribute__((ext_vector_type(4))) float f32x4;

// ---------- helpers ----------
__device__ __forceinline__ unsigned fenc(float f) {
    unsigned u = __float_as_uint(f);
    return (u & 0x80000000u) ? ~u : (u | 0x80000000u);
}
__device__ __forceinline__ float fdec(unsigned e) {
    unsigned u = (e & 0x80000000u) ? (e & 0x7FFFFFFFu) : ~e;
    return __uint_as_float(u);
}
__device__ __forceinline__ unsigned short f2bf(float f) {   // RNE f32 -> bf16
    unsigned u = __float_as_uint(f);
    u += 0x7FFFu + ((u >> 16) & 1u);
    return (unsigned short)(u >> 16);
}

// async global load: compiler cannot serialize volatile asm loads
__device__ __forceinline__ f32x4 gload4(const float* p) {
    f32x4 r;
    asm volatile("global_load_dwordx4 %0, %1, off" : "=v"(r) : "v"(p));
    return r;
}

__device__ __forceinline__ float block_sum(float v, float* red) {
    red[threadIdx.x] = v;
    __syncthreads();
    for (int k = 128; k > 0; k >>= 1) {
        if (threadIdx.x < k) red[threadIdx.x] += red[threadIdx.x + k];
        __syncthreads();
    }
    float r = red[0];
    __syncthreads();
    return r;
}
__device__ __forceinline__ float block_max(float v, float* red) {
    red[threadIdx.x] = v;
    __syncthreads();
    for (int k = 128; k > 0; k >>= 1) {
        if (threadIdx.x < k) red[threadIdx.x] = fmaxf(red[threadIdx.x], red[threadIdx.x + k]);
        __syncthreads();
    }
    float r = red[0];
    __syncthreads();
    return r;
}

// ---------- kernels ----------
// FUSED prepass (r27 version): blocks [0,64) = histogram; [64,64+B/4) = per-row
// 1/max(||f||,eps); [64+B/4, 64+B/2) = per-row logsumexp(logits).
__global__ __launch_bounds__(256) void k_pre(const int* tgt, int* gh,
                                             const float* feat, float* fnorminv,
                                             const float* logits, float* lse,
                                             int B, int D, int C2) {
    __shared__ int lh[1024];
    int t = threadIdx.x;
    int bid = blockIdx.x;
    if (bid < 64) {
        int g = bid;
        lh[t] = 0; lh[t + 256] = 0; lh[t + 512] = 0; lh[t + 768] = 0;
        __syncthreads();
        int i = g * 256 + t;
        if (i < B) atomicAdd(&lh[tgt[i]], 1);
        __syncthreads();
        int* dst = gh + g * 1024;
        dst[t] = lh[t]; dst[t + 256] = lh[t + 256];
        dst[t + 512] = lh[t + 512]; dst[t + 768] = lh[t + 768];
        return;
    }
    int wid = t >> 6, lane = t & 63;
    int nf = B / 4;
    if (bid < 64 + nf) {
        int row = (bid - 64) * 4 + wid;
        const float4* f4 = (const float4*)(feat + (long)row * D);
        float ss = 0.f;
#pragma unroll
        for (int k = 0; k < 4; k++) {
            float4 v = f4[lane + 64 * k];
            ss += v.x * v.x + v.y * v.y + v.z * v.z + v.w * v.w;
        }
#pragma unroll
        for (int o = 32; o > 0; o >>= 1) ss += __shfl_xor(ss, o);
        if (lane == 0) fnorminv[row] = 1.f / fmaxf(sqrtf(ss), EPS);
    } else {
        int row = (bid - 64 - nf) * 4 + wid;
        const float4* l4 = (const float4*)(logits + (long)row * C2);
        int Q = C2 >> 2;    // 250
        float ta[16];
        float m = -INFINITY;
#pragma unroll
        for (int k = 0; k < 4; k++) {
            int j = lane + 64 * k;
            if (j < Q) {
                float4 v = l4[j];
                ta[4 * k] = v.x; ta[4 * k + 1] = v.y; ta[4 * k + 2] = v.z; ta[4 * k + 3] = v.w;
                m = fmaxf(m, fmaxf(fmaxf(v.x, v.y), fmaxf(v.z, v.w)));
            } else {
#pragma unroll
                for (int r = 0; r < 4; r++) ta[4 * k + r] = -INFINITY;
            }
        }
#pragma unroll
        for (int o = 32; o > 0; o >>= 1) m = fmaxf(m, __shfl_xor(m, o));
        float s = 0.f;
#pragma unroll
        for (int i = 0; i < 16; i++)
            if (ta[i] != -INFINITY) s += __expf(ta[i] - m);
#pragma unroll
        for (int o = 32; o > 0; o >>= 1) s += __shfl_xor(s, o);
        if (lane == 0) lse[row] = m + __logf(s);
    }
}

__global__ void k_bases(int* gh, int* counts, int* offsets, unsigned* minmax, int G, int C) {
    __shared__ int buf[1024];
    int c = threadIdx.x;
    if (c == 0) { minmax[0] = 0xFFFFFFFFu; minmax[1] = 0u; }
    int run = 0;
#pragma unroll 16
    for (int g = 0; g < G; g++) {
        int v = gh[g * 1024 + c];
        gh[g * 1024 + c] = run;
        run += v;
    }
    if (c < C) counts[c] = run;
    int v0 = (c < C) ? run : 0;
    buf[c] = v0;
    __syncthreads();
    for (int off = 1; off < 1024; off <<= 1) {
        int v = (c >= off) ? buf[c - off] : 0;
        __syncthreads();
        buf[c] += v;
        __syncthreads();
    }
    if (c < C) offsets[c] = buf[c] - v0;
}

__global__ void k_rank_scatter(const int* tgt, const int* offsets, const int* gh,
                               int* idx, int B) {
    __shared__ int lt[256];
    int g = blockIdx.x, t = threadIdx.x;
    int i = g * 256 + t;
    int my = (i < B) ? tgt[i] : -1;
    lt[t] = my;
    __syncthreads();
    if (i < B) {
        int rank = 0;
        for (int j = 0; j < t; j++) rank += (lt[j] == my);
        idx[offsets[my] + gh[g * 1024 + my] + rank] = i;
    }
}

// FUSED table build: blocks [0,C) -> feature table + norms + g; blocks [C,2C) ->
// logit table. Row loads issued as inline-asm global_load_dwordx4 in batches of 8
// with one tied vmcnt(0): compiler cannot serialize -> true depth-8 pipeline.
// Ascending accumulation order (deterministic).
__global__ __launch_bounds__(256) void k_tables(const float* feat, const float* finit,
                                                const float* logits, const float* linit,
                                                const int* counts, const int* offsets,
                                                const int* idx, const float* fnorminv,
                                                float* ftab, float* ltab, float* norms,
                                                float* gsum,
                                                int C, int D, int C2) {
    __shared__ float red[256];
    int t = threadIdx.x;
    int lane = t & 63;
    if ((int)blockIdx.x < C) {
        int c = blockIdx.x;
        int n = counts[c];
        float o0, o1, o2, o3;
        float4 acc2 = {0.f, 0.f, 0.f, 0.f};
        if (n == 0) {
            float4 v = ((const float4*)(finit + (long)c * D))[t];
            o0 = v.x; o1 = v.y; o2 = v.z; o3 = v.w;
        } else {
            int o = offsets[c];
            float4 acc = {0.f, 0.f, 0.f, 0.f};
            for (int base = 0; base < n; base += 64) {
                int m = min(64, n - base);
                int lid = idx[o + base + min(lane, m - 1)];
                float fvl = fnorminv[lid];
                int m8 = m & ~7;
                int j = 0;
                for (; j < m8; j += 8) {
                    int i0 = __shfl(lid, j),     i1 = __shfl(lid, j + 1);
                    int i2 = __shfl(lid, j + 2), i3 = __shfl(lid, j + 3);
                    int i4 = __shfl(lid, j + 4), i5 = __shfl(lid, j + 5);
                    int i6 = __shfl(lid, j + 6), i7 = __shfl(lid, j + 7);
                    float f0 = __shfl(fvl, j),     f1 = __shfl(fvl, j + 1);
                    float f2 = __shfl(fvl, j + 2), f3 = __shfl(fvl, j + 3);
                    float f4_ = __shfl(fvl, j + 4), f5 = __shfl(fvl, j + 5);
                    float f6 = __shfl(fvl, j + 6), f7 = __shfl(fvl, j + 7);
                    f32x4 v0 = gload4(feat + (long)i0 * D + t * 4);
                    f32x4 v1 = gload4(feat + (long)i1 * D + t * 4);
                    f32x4 v2 = gload4(feat + (long)i2 * D + t * 4);
                    f32x4 v3 = gload4(feat + (long)i3 * D + t * 4);
                    f32x4 v4 = gload4(feat + (long)i4 * D + t * 4);
                    f32x4 v5 = gload4(feat + (long)i5 * D + t * 4);
                    f32x4 v6 = gload4(feat + (long)i6 * D + t * 4);
                    f32x4 v7 = gload4(feat + (long)i7 * D + t * 4);
                    asm volatile("s_waitcnt vmcnt(0)"
                                 : "+v"(v0), "+v"(v1), "+v"(v2), "+v"(v3),
                                   "+v"(v4), "+v"(v5), "+v"(v6), "+v"(v7));
                    __builtin_amdgcn_sched_barrier(0);
                    acc.x += v0[0]; acc.y += v0[1]; acc.z += v0[2]; acc.w += v0[3];
                    acc2.x += v0[0] * f0; acc2.y += v0[1] * f0; acc2.z += v0[2] * f0; acc2.w += v0[3] * f0;
                    acc.x += v1[0]; acc.y += v1[1]; acc.z += v1[2]; acc.w += v1[3];
                    acc2.x += v1[0] * f1; acc2.y += v1[1] * f1; acc2.z += v1[2] * f1; acc2.w += v1[3] * f1;
                    acc.x += v2[0]; acc.y += v2[1]; acc.z += v2[2]; acc.w += v2[3];
                    acc2.x += v2[0] * f2; acc2.y += v2[1] * f2; acc2.z += v2[2] * f2; acc2.w += v2[3] * f2;
                    acc.x += v3[0]; acc.y += v3[1]; acc.z += v3[2]; acc.w += v3[3];
                    acc2.x += v3[0] * f3; acc2.y += v3[1] * f3; acc2.z += v3[2] * f3; acc2.w += v3[3] * f3;
                    acc.x += v4[0]; acc.y += v4[1]; acc.z += v4[2]; acc.w += v4[3];
                    acc2.x += v4[0] * f4_; acc2.y += v4[1] * f4_; acc2.z += v4[2] * f4_; acc2.w += v4[3] * f4_;
                    acc.x += v5[0]; acc.y += v5[1]; acc.z += v5[2]; acc.w += v5[3];
                    acc2.x += v5[0] * f5; acc2.y += v5[1] * f5; acc2.z += v5[2] * f5; acc2.w += v5[3] * f5;
                    acc.x += v6[0]; acc.y += v6[1]; acc.z += v6[2]; acc.w += v6[3];
                    acc2.x += v6[0] * f6; acc2.y += v6[1] * f6; acc2.z += v6[2] * f6; acc2.w += v6[3] * f6;
                    acc.x += v7[0]; acc.y += v7[1]; acc.z += v7[2]; acc.w += v7[3];
                    acc2.x += v7[0] * f7; acc2.y += v7[1] * f7; acc2.z += v7[2] * f7; acc2.w += v7[3] * f7;
                }
                for (; j < m; j++) {
                    int i0 = __shfl(lid, j);
                    float f0 = __shfl(fvl, j);
                    float4 v0 = ((const float4*)(feat + (long)i0 * D))[t];
                    acc.x += v0.x; acc.y += v0.y; acc.z += v0.z; acc.w += v0.w;
                    acc2.x += v0.x * f0; acc2.y += v0.y * f0; acc2.z += v0.z * f0; acc2.w += v0.w * f0;
                }
            }
            float inv = 1.0f / (float)n;
            o0 = acc.x * inv; o1 = acc.y * inv; o2 = acc.z * inv; o3 = acc.w * inv;
        }
        float* dst = ftab + (long)c * D + t * 4;
        dst[0] = o0; dst[1] = o1; dst[2] = o2; dst[3] = o3;
        if (n > 0) ((float4*)(gsum + (long)c * D))[t] = acc2;
        float ss = o0 * o0 + o1 * o1 + o2 * o2 + o3 * o3;
        ss = block_sum(ss, red);
        if (t == 0) norms[c] = sqrtf(ss);
    } else {
        int c = blockIdx.x - C;
        int n = counts[c];
        int nv = C2 >> 2;                           // 250
        if (n == 0) {
            for (int d = t; d < C2; d += 256) ltab[(long)c * C2 + d] = linit[(long)c * C2 + d];
            return;
        }
        int tc = min(t, nv - 1);
        int o = offsets[c];
        float4 acc = {0.f, 0.f, 0.f, 0.f};
        for (int base = 0; base < n; base += 64) {
            int m = min(64, n - base);
            int lid = idx[o + base + min(lane, m - 1)];
            int m8 = m & ~7;
            int j = 0;
            for (; j < m8; j += 8) {
                int i0 = __shfl(lid, j),     i1 = __shfl(lid, j + 1);
                int i2 = __shfl(lid, j + 2), i3 = __shfl(lid, j + 3);
                int i4 = __shfl(lid, j + 4), i5 = __shfl(lid, j + 5);
                int i6 = __shfl(lid, j + 6), i7 = __shfl(lid, j + 7);
                f32x4 v0 = gload4(logits + (long)i0 * C2 + tc * 4);
                f32x4 v1 = gload4(logits + (long)i1 * C2 + tc * 4);
                f32x4 v2 = gload4(logits + (long)i2 * C2 + tc * 4);
                f32x4 v3 = gload4(logits + (long)i3 * C2 + tc * 4);
                f32x4 v4 = gload4(logits + (long)i4 * C2 + tc * 4);
                f32x4 v5 = gload4(logits + (long)i5 * C2 + tc * 4);
                f32x4 v6 = gload4(logits + (long)i6 * C2 + tc * 4);
                f32x4 v7 = gload4(logits + (long)i7 * C2 + tc * 4);
                asm volatile("s_waitcnt vmcnt(0)"
                             : "+v"(v0), "+v"(v1), "+v"(v2), "+v"(v3),
                               "+v"(v4), "+v"(v5), "+v"(v6), "+v"(v7));
                __builtin_amdgcn_sched_barrier(0);
                acc.x += v0[0]; acc.y += v0[1]; acc.z += v0[2]; acc.w += v0[3];
                acc.x += v1[0]; acc.y += v1[1]; acc.z += v1[2]; acc.w += v1[3];
                acc.x += v2[0]; acc.y += v2[1]; acc.z += v2[2]; acc.w += v2[3];
                acc.x += v3[0]; acc.y += v3[1]; acc.z += v3[2]; acc.w += v3[3];
                acc.x += v4[0]; acc.y += v4[1]; acc.z += v4[2]; acc.w += v4[3];
                acc.x += v5[0]; acc.y += v5[1]; acc.z += v5[2]; acc.w += v5[3];
                acc.x += v6[0]; acc.y += v6[1]; acc.z += v6[2]; acc.w += v6[3];
                acc.x += v7[0]; acc.y += v7[1]; acc.z += v7[2]; acc.w += v7[3];
            }
            for (; j < m; j++) {
                int i0 = __shfl(lid, j);
                float4 v0 = *(const float4*)(logits + (long)i0 * C2 + tc * 4);
                acc.x += v0.x; acc.y += v0.y; acc.z += v0.z; acc.w += v0.w;
            }
        }
        if (t < nv) {
            float inv = 1.0f / (float)n;
            float* dst = ltab + (long)c * C2 + t * 4;
            dst[0] = acc.x * inv;
            dst[1] = acc.y * inv;
            dst[2] = acc.z * inv;
            dst[3] = acc.w * inv;
        }
    }
}

// Triangular raw-dot GEMM via bf16 MFMA: one block per upper-tri 64x64 tile.
__global__ __launch_bounds__(1024) void k_gemm(const float* A, float* S,
                                               int C, int D, int NT) {
    __shared__ __align__(16) unsigned short As[2][64][40];
    __shared__ __align__(16) unsigned short Bs[2][64][40];
    __shared__ __align__(16) float racc[64 * 68];
    int t = threadIdx.x;

    int q = blockIdx.x, ti = 0;
    while (q >= NT - ti) { q -= NT - ti; ti++; }
    int tj = ti + q;
    int rb = ti * 64, cb = tj * 64;

    int srow = t >> 4;
    int skq = (t & 15) * 2;
    int ga = rb + srow, gb = cb + srow;
    bool okA = ga < C, okB = gb < C;
    const float* arow = A + (long)ga * D;
    const float* brow = A + (long)gb * D;

    int w = t >> 6, wr = w >> 2, wc = w & 3;
    int l = t & 63, fr = l & 15, fb = l >> 4;
    int arl = wr * 16 + fr, brl = wc * 16 + fr, koff = fb * 8;

    {
        float2 z2 = {0.f, 0.f};
        float2 pa = okA ? *(const float2*)(arow + skq) : z2;
        float2 pb = okB ? *(const float2*)(brow + skq) : z2;
        As[0][srow][skq] = f2bf(pa.x); As[0][srow][skq + 1] = f2bf(pa.y);
        Bs[0][srow][skq] = f2bf(pb.x); Bs[0][srow][skq + 1] = f2bf(pb.y);
    }
    __syncthreads();

    f32x4 acc = {0.f, 0.f, 0.f, 0.f};
    int nsteps = D >> 5;               // 32
    for (int step = 0; step < nsteps; step++) {
        int cur = step & 1;
        float2 pa, pb;
        if (step < nsteps - 1) {
            int k0n = (step + 1) * 32;
            float2 z2 = {0.f, 0.f};
            pa = okA ? *(const float2*)(arow + k0n + skq) : z2;
            pb = okB ? *(const float2*)(brow + k0n + skq) : z2;
        }
        short8v af = *reinterpret_cast<const short8v*>(&As[cur][arl][koff]);
        short8v bf = *reinterpret_cast<const short8v*>(&Bs[cur][brl][koff]);
        acc = __builtin_amdgcn_mfma_f32_16x16x32_bf16(af, bf, acc, 0, 0, 0);
        if (step < nsteps - 1) {
            int nb = cur ^ 1;
            As[nb][srow][skq] = f2bf(pa.x); As[nb][srow][skq + 1] = f2bf(pa.y);
            Bs[nb][srow][skq] = f2bf(pb.x); Bs[nb][srow][skq + 1] = f2bf(pb.y);
        }
        __syncthreads();
    }

#pragma unroll
    for (int r = 0; r < 4; r++)
        racc[(wr * 16 + fb * 4 + r) * 68 + wc * 16 + fr] = acc[r];
    __syncthreads();

    int r0 = t >> 4;
    int cbl = (t & 15) * 4;
    int gr = rb + r0;
    bool edge = (tj == NT - 1);
    if (gr < C) {
        float4 v4 = *reinterpret_cast<const float4*>(&racc[r0 * 68 + cbl]);
        float v[4] = {v4.x, v4.y, v4.z, v4.w};
        float* dst = S + (long)gr * C + cb + cbl;
        if (!edge) {
            *reinterpret_cast<float2*>(dst) = make_float2(v[0], v[1]);
            *reinterpret_cast<float2*>(dst + 2) = make_float2(v[2], v[3]);
        } else {
#pragma unroll
            for (int m = 0; m < 4; m++)
                if (cb + cbl + m < C) dst[m] = v[m];
        }
    }
    if (ti != tj) {
        int cc0 = cb + r0;
        if (cc0 < C) {
            float wv[4];
#pragma unroll
            for (int m = 0; m < 4; m++) wv[m] = racc[(cbl + m) * 68 + r0];
            float* dst = S + (long)cc0 * C + rb + cbl;
            *reinterpret_cast<float2*>(dst) = make_float2(wv[0], wv[1]);
            *reinterpret_cast<float2*>(dst + 2) = make_float2(wv[2], wv[3]);
        }
    }
}

// per-row: best/argmax (excl diag) of cos values + global min/max (incl diag).
__global__ void k_rowmax(const float* S, const float* norms, unsigned* minmax,
                         float* simraw, int* simcls, int C) {
    __shared__ float invn[1024];
    __shared__ float rv[256], rmn[256], rmx[256];
    __shared__ int ri[256];
    int c = blockIdx.x, t = threadIdx.x;
    for (int j = t; j < C; j += 256) invn[j] = 1.f / norms[j];
    __syncthreads();
    float inc = invn[c];
    float best = -INFINITY, lmin = INFINITY, lmax = -INFINITY;
    int bi = 0x7FFFFFFF;
    long rowo = (long)c * C;
    for (int j = t; j < C; j += 256) {
        float v = S[rowo + j] * inc * invn[j];
        lmin = fminf(lmin, v);
        lmax = fmaxf(lmax, v);
        if (j != c && v > best) { best = v; bi = j; }
    }
    rv[t] = best; ri[t] = bi; rmn[t] = lmin; rmx[t] = lmax;
    __syncthreads();
    for (int k = 128; k > 0; k >>= 1) {
        if (t < k) {
            if (rv[t + k] > rv[t] || (rv[t + k] == rv[t] && ri[t + k] < ri[t])) {
                rv[t] = rv[t + k];
                ri[t] = ri[t + k];
            }
            rmn[t] = fminf(rmn[t], rmn[t + k]);
            rmx[t] = fmaxf(rmx[t], rmx[t + k]);
        }
        __syncthreads();
    }
    if (t == 0) {
        simraw[c] = rv[0];
        simcls[c] = ri[0];
        atomicMin(&minmax[0], fenc(rmn[0]));
        atomicMax(&minmax[1], fenc(rmx[0]));
    }
}

// Per-class losses via factored identities:
//  cpf[c] = n_c - dot(g_c,u_c)/max(|u_c|,eps) + sv_c*dot(g_c,v_c)/max(|v_c|,eps)
//  cpk[c] = LSE_c - n_c*lse(ltab_c)
__global__ __launch_bounds__(256) void k_closs(const float* gsum, const float* ftab,
                                               const float* norms, const int* counts,
                                               const int* offsets, const int* idx,
                                               const float* lse, const float* ltab,
                                               const unsigned* minmax, const float* simraw,
                                               const int* simcls,
                                               float* cpf, float* cpk,
                                               int C, int D, int C2) {
    __shared__ float red[256];
    int c = blockIdx.x, t = threadIdx.x;
    int n = counts[c];
    if (n == 0) {
        if (t == 0) { cpf[c] = 0.f; cpk[c] = 0.f; }
        return;
    }
    int sc = simcls[c];
    float4 g4 = ((const float4*)(gsum + (long)c * D))[t];
    const float* u = ftab + (long)c * D + t * 4;
    const float* v = ftab + (long)sc * D + t * 4;
    float d1 = g4.x * u[0] + g4.y * u[1] + g4.z * u[2] + g4.w * u[3];
    float d2 = g4.x * v[0] + g4.y * v[1] + g4.z * v[2] + g4.w * v[3];
    d1 = block_sum(d1, red);
    d2 = block_sum(d2, red);
    float ta[4];
    float lm = -INFINITY;
#pragma unroll
    for (int k = 0; k < 4; k++) {
        int j = t + k * 256;
        if (j < C2) { ta[k] = ltab[(long)c * C2 + j]; lm = fmaxf(lm, ta[k]); }
        else ta[k] = -INFINITY;
    }
    lm = block_max(lm, red);
    float se = 0.f;
#pragma unroll
    for (int k = 0; k < 4; k++)
        if (ta[k] != -INFINITY) se += __expf(ta[k] - lm);
    se = block_sum(se, red);
    float ls = 0.f;
    int o = offsets[c];
    for (int i = t; i < n; i += 256) ls += lse[idx[o + i]];
    ls = block_sum(ls, red);
    if (t == 0) {
        float cmin = fdec(minmax[0]);
        float cmax = fdec(minmax[1]);
        float sv = (simraw[c] - cmin) / (cmax - cmin);
        float nu = fmaxf(norms[c], EPS);
        float nv = fmaxf(norms[sc], EPS);
        cpf[c] = (float)n - d1 / nu + sv * d2 / nv;
        cpk[c] = ls - (float)n * (lm + __logf(se));
    }
}

__global__ void k_final(const float* cpf, const float* cpk, float* out, int C) {
    __shared__ float red[256];
    float a = 0.f;
    for (int i = threadIdx.x; i < C; i += 256) a += cpf[i];
    a = block_sum(a, red);
    float b = 0.f;
    for (int i = threadIdx.x; i < C; i += 256) b += cpk[i];
    b = block_sum(b, red);
    if (threadIdx.x == 0) {
        out[0] = a;
        out[1] = b;
    }
}

extern "C" void kernel_launch(void* const* d_in, const int* in_sizes, int n_in,
                              void* d_out, int out_size, void* d_ws, size_t ws_size,
                              hipStream_t stream) {
    const float* feature = (const float*)d_in[0];
    const float* logits  = (const float*)d_in[1];
    const int*   targets = (const int*)d_in[2];
    const float* finit   = (const float*)d_in[3];
    const float* linit   = (const float*)d_in[4];

    const int B = in_sizes[2];                 // 16384
    const int D = in_sizes[0] / B;             // 1024
    const int C = in_sizes[3] / D;             // 1000

    float* out = (float*)d_out;
    float* ftab = out + 2;                     // [C, D]
    float* ltab = out + 2 + (long)C * D;       // [C, C]

    const int G = 64;                          // histogram groups
    const int NT = (C + 63) / 64;              // 16 tiles per dim
    const int NTRI = NT * (NT + 1) / 2;        // 136 triangular tiles

    char* ws = (char*)d_ws;
    int*      counts   = (int*)(ws + 0);          // 4KB
    int*      offsets  = (int*)(ws + 4096);       // 4KB
    int*      idx      = (int*)(ws + 12288);      // 64KB
    float*    norms    = (float*)(ws + 77824);    // 4KB
    float*    simraw   = (float*)(ws + 81920);    // 4KB
    int*      simcls   = (int*)(ws + 86016);      // 4KB
    unsigned* minmax   = (unsigned*)(ws + 90112); // 8B
    float*    cpf      = (float*)(ws + 90368);    // 4KB
    float*    cpk      = (float*)(ws + 94464);    // 4KB
    float*    fnorminv = (float*)(ws + 98560);    // 64KB
    float*    lse      = (float*)(ws + 164096);   // 64KB
    float*    Sws      = (float*)(ws + 262144);   // C*C floats = 4MB
    float*    gsum     = (float*)(ws + 262144 + (size_t)C * C * sizeof(float)); // C*D

    float* S = Sws;                            // ws_size >= 12.25MB proven (round 12)

    // gh scratch lives in the (not-yet-written) ltab output region
    int* gh = (int*)ltab;

    // prepass: histogram + per-row 1/|f| + per-row lse (streams both inputs)
    k_pre<<<64 + B / 2, 256, 0, stream>>>(targets, gh, feature, fnorminv,
                                          logits, lse, B, D, C);
    k_bases<<<1, 1024, 0, stream>>>(gh, counts, offsets, minmax, G, C);
    k_rank_scatter<<<G, 256, 0, stream>>>(targets, offsets, gh, idx, B);

    // both gathers in one dispatch; feature path also accumulates g = sum(f/|f|)
    k_tables<<<2 * C, 256, 0, stream>>>(feature, finit, logits, linit,
                                        counts, offsets, idx, fnorminv,
                                        ftab, ltab, norms, gsum, C, D, C);

    k_gemm<<<NTRI, 1024, 0, stream>>>(ftab, S, C, D, NT);
    k_rowmax<<<C, 256, 0, stream>>>(S, norms, minmax, simraw, simcls, C);
    k_closs<<<C, 256, 0, stream>>>(gsum, ftab, norms, counts, offsets, idx,
                                   lse, ltab, minmax, simraw, simcls, cpf, cpk, C, D, C);
    k_final<<<1, 256, 0, stream>>>(cpf, cpk, out, C);
}

// Round 30
// 133.209 us; speedup vs baseline: 1.0299x; 1.0052x over previous
//
#include <hip/hip_runtime.h>
#include <hip/hip_bf16.h>
#include <math.h>

#define EPS 1e-8f

typedef __attribute__((ext_vector_type(8))) short short8v;
typedef __attribute__((ext_vector_type(4))) float f32x4;

// ---------- helpers ----------
__device__ __forceinline__ unsigned fenc(float f) {
    unsigned u = __float_as_uint(f);
    return (u & 0x80000000u) ? ~u : (u | 0x80000000u);
}
__device__ __forceinline__ float fdec(unsigned e) {
    unsigned u = (e & 0x80000000u) ? (e & 0x7FFFFFFFu) : ~e;
    return __uint_as_float(u);
}
__device__ __forceinline__ unsigned short f2bf(float f) {   // RNE f32 -> bf16
    unsigned u = __float_as_uint(f);
    u += 0x7FFFu + ((u >> 16) & 1u);
    return (unsigned short)(u >> 16);
}

// async global load: compiler cannot serialize volatile asm loads
__device__ __forceinline__ f32x4 gload4(const float* p) {
    f32x4 r;
    asm volatile("global_load_dwordx4 %0, %1, off" : "=v"(r) : "v"(p));
    return r;
}

__device__ __forceinline__ float block_sum(float v, float* red) {
    red[threadIdx.x] = v;
    __syncthreads();
    for (int k = 128; k > 0; k >>= 1) {
        if (threadIdx.x < k) red[threadIdx.x] += red[threadIdx.x + k];
        __syncthreads();
    }
    float r = red[0];
    __syncthreads();
    return r;
}
__device__ __forceinline__ float block_max(float v, float* red) {
    red[threadIdx.x] = v;
    __syncthreads();
    for (int k = 128; k > 0; k >>= 1) {
        if (threadIdx.x < k) red[threadIdx.x] = fmaxf(red[threadIdx.x], red[threadIdx.x + k]);
        __syncthreads();
    }
    float r = red[0];
    __syncthreads();
    return r;
}

// ---------- kernels ----------
// FUSED prepass: blocks [0,64) = histogram; blocks [64, 64+2048) = persistent
// grid-stride waves over 2B row-tasks (task<B: feature 1/||f||; else: lse of
// logits row). Loads issued via asm batch-4 (true depth-4); per-lane
// accumulation order identical to r27 -> bitwise-identical outputs.
__global__ __launch_bounds__(256) void k_pre(const int* tgt, int* gh,
                                             const float* feat, float* fnorminv,
                                             const float* logits, float* lse,
                                             int B, int D, int C2) {
    __shared__ int lh[1024];
    int t = threadIdx.x;
    int bid = blockIdx.x;
    if (bid < 64) {
        int g = bid;
        lh[t] = 0; lh[t + 256] = 0; lh[t + 512] = 0; lh[t + 768] = 0;
        __syncthreads();
        int i = g * 256 + t;
        if (i < B) atomicAdd(&lh[tgt[i]], 1);
        __syncthreads();
        int* dst = gh + g * 1024;
        dst[t] = lh[t]; dst[t + 256] = lh[t + 256];
        dst[t + 512] = lh[t + 512]; dst[t + 768] = lh[t + 768];
        return;
    }
    int wid = t >> 6, lane = t & 63;
    int gw = (bid - 64) * 4 + wid;          // global wave id, 0..8191
    const int NW = 2048 * 4;                // 8192 persistent waves
    for (int task = gw; task < 2 * B; task += NW) {
        if (task < B) {
            // ---- feature inverse norm ----
            int row = task;
            const float* fp = feat + (long)row * D;
            f32x4 v0 = gload4(fp + (long)lane * 4);
            f32x4 v1 = gload4(fp + (long)(lane + 64) * 4);
            f32x4 v2 = gload4(fp + (long)(lane + 128) * 4);
            f32x4 v3 = gload4(fp + (long)(lane + 192) * 4);
            asm volatile("s_waitcnt vmcnt(0)"
                         : "+v"(v0), "+v"(v1), "+v"(v2), "+v"(v3));
            __builtin_amdgcn_sched_barrier(0);
            float ss = 0.f;
            ss += v0[0] * v0[0] + v0[1] * v0[1] + v0[2] * v0[2] + v0[3] * v0[3];
            ss += v1[0] * v1[0] + v1[1] * v1[1] + v1[2] * v1[2] + v1[3] * v1[3];
            ss += v2[0] * v2[0] + v2[1] * v2[1] + v2[2] * v2[2] + v2[3] * v2[3];
            ss += v3[0] * v3[0] + v3[1] * v3[1] + v3[2] * v3[2] + v3[3] * v3[3];
#pragma unroll
            for (int o = 32; o > 0; o >>= 1) ss += __shfl_xor(ss, o);
            if (lane == 0) fnorminv[row] = 1.f / fmaxf(sqrtf(ss), EPS);
        } else {
            // ---- logits logsumexp ----
            int row = task - B;
            const float* lp = logits + (long)row * C2;
            int Q = C2 >> 2;                 // 250 float4 per row
            bool ok3 = (lane + 192) < Q;     // lane < 58
            int j3 = ok3 ? (lane + 192) : (Q - 1);
            f32x4 v0 = gload4(lp + (long)lane * 4);
            f32x4 v1 = gload4(lp + (long)(lane + 64) * 4);
            f32x4 v2 = gload4(lp + (long)(lane + 128) * 4);
            f32x4 v3 = gload4(lp + (long)j3 * 4);
            asm volatile("s_waitcnt vmcnt(0)"
                         : "+v"(v0), "+v"(v1), "+v"(v2), "+v"(v3));
            __builtin_amdgcn_sched_barrier(0);
            float m = -INFINITY;
            m = fmaxf(m, fmaxf(fmaxf(v0[0], v0[1]), fmaxf(v0[2], v0[3])));
            m = fmaxf(m, fmaxf(fmaxf(v1[0], v1[1]), fmaxf(v1[2], v1[3])));
            m = fmaxf(m, fmaxf(fmaxf(v2[0], v2[1]), fmaxf(v2[2], v2[3])));
            if (ok3) m = fmaxf(m, fmaxf(fmaxf(v3[0], v3[1]), fmaxf(v3[2], v3[3])));
#pragma unroll
            for (int o = 32; o > 0; o >>= 1) m = fmaxf(m, __shfl_xor(m, o));
            float s = 0.f;
            s += __expf(v0[0] - m) + __expf(v0[1] - m) + __expf(v0[2] - m) + __expf(v0[3] - m);
            s += __expf(v1[0] - m) + __expf(v1[1] - m) + __expf(v1[2] - m) + __expf(v1[3] - m);
            s += __expf(v2[0] - m) + __expf(v2[1] - m) + __expf(v2[2] - m) + __expf(v2[3] - m);
            if (ok3)
                s += __expf(v3[0] - m) + __expf(v3[1] - m) + __expf(v3[2] - m) + __expf(v3[3] - m);
#pragma unroll
            for (int o = 32; o > 0; o >>= 1) s += __shfl_xor(s, o);
            if (lane == 0) lse[row] = m + __logf(s);
        }
    }
}

__global__ void k_bases(int* gh, int* counts, int* offsets, unsigned* minmax, int G, int C) {
    __shared__ int buf[1024];
    int c = threadIdx.x;
    if (c == 0) { minmax[0] = 0xFFFFFFFFu; minmax[1] = 0u; }
    int run = 0;
#pragma unroll 16
    for (int g = 0; g < G; g++) {
        int v = gh[g * 1024 + c];
        gh[g * 1024 + c] = run;
        run += v;
    }
    if (c < C) counts[c] = run;
    int v0 = (c < C) ? run : 0;
    buf[c] = v0;
    __syncthreads();
    for (int off = 1; off < 1024; off <<= 1) {
        int v = (c >= off) ? buf[c - off] : 0;
        __syncthreads();
        buf[c] += v;
        __syncthreads();
    }
    if (c < C) offsets[c] = buf[c] - v0;
}

__global__ void k_rank_scatter(const int* tgt, const int* offsets, const int* gh,
                               int* idx, int B) {
    __shared__ int lt[256];
    int g = blockIdx.x, t = threadIdx.x;
    int i = g * 256 + t;
    int my = (i < B) ? tgt[i] : -1;
    lt[t] = my;
    __syncthreads();
    if (i < B) {
        int rank = 0;
        for (int j = 0; j < t; j++) rank += (lt[j] == my);
        idx[offsets[my] + gh[g * 1024 + my] + rank] = i;
    }
}

// FUSED table build (r29): blocks [0,C) -> feature table + norms + g; blocks
// [C,2C) -> logit table. Row loads via asm batch-8 + one vmcnt(0). Deterministic.
__global__ __launch_bounds__(256) void k_tables(const float* feat, const float* finit,
                                                const float* logits, const float* linit,
                                                const int* counts, const int* offsets,
                                                const int* idx, const float* fnorminv,
                                                float* ftab, float* ltab, float* norms,
                                                float* gsum,
                                                int C, int D, int C2) {
    __shared__ float red[256];
    int t = threadIdx.x;
    int lane = t & 63;
    if ((int)blockIdx.x < C) {
        int c = blockIdx.x;
        int n = counts[c];
        float o0, o1, o2, o3;
        float4 acc2 = {0.f, 0.f, 0.f, 0.f};
        if (n == 0) {
            float4 v = ((const float4*)(finit + (long)c * D))[t];
            o0 = v.x; o1 = v.y; o2 = v.z; o3 = v.w;
        } else {
            int o = offsets[c];
            float4 acc = {0.f, 0.f, 0.f, 0.f};
            for (int base = 0; base < n; base += 64) {
                int m = min(64, n - base);
                int lid = idx[o + base + min(lane, m - 1)];
                float fvl = fnorminv[lid];
                int m8 = m & ~7;
                int j = 0;
                for (; j < m8; j += 8) {
                    int i0 = __shfl(lid, j),     i1 = __shfl(lid, j + 1);
                    int i2 = __shfl(lid, j + 2), i3 = __shfl(lid, j + 3);
                    int i4 = __shfl(lid, j + 4), i5 = __shfl(lid, j + 5);
                    int i6 = __shfl(lid, j + 6), i7 = __shfl(lid, j + 7);
                    float f0 = __shfl(fvl, j),     f1 = __shfl(fvl, j + 1);
                    float f2 = __shfl(fvl, j + 2), f3 = __shfl(fvl, j + 3);
                    float f4_ = __shfl(fvl, j + 4), f5 = __shfl(fvl, j + 5);
                    float f6 = __shfl(fvl, j + 6), f7 = __shfl(fvl, j + 7);
                    f32x4 v0 = gload4(feat + (long)i0 * D + t * 4);
                    f32x4 v1 = gload4(feat + (long)i1 * D + t * 4);
                    f32x4 v2 = gload4(feat + (long)i2 * D + t * 4);
                    f32x4 v3 = gload4(feat + (long)i3 * D + t * 4);
                    f32x4 v4 = gload4(feat + (long)i4 * D + t * 4);
                    f32x4 v5 = gload4(feat + (long)i5 * D + t * 4);
                    f32x4 v6 = gload4(feat + (long)i6 * D + t * 4);
                    f32x4 v7 = gload4(feat + (long)i7 * D + t * 4);
                    asm volatile("s_waitcnt vmcnt(0)"
                                 : "+v"(v0), "+v"(v1), "+v"(v2), "+v"(v3),
                                   "+v"(v4), "+v"(v5), "+v"(v6), "+v"(v7));
                    __builtin_amdgcn_sched_barrier(0);
                    acc.x += v0[0]; acc.y += v0[1]; acc.z += v0[2]; acc.w += v0[3];
                    acc2.x += v0[0] * f0; acc2.y += v0[1] * f0; acc2.z += v0[2] * f0; acc2.w += v0[3] * f0;
                    acc.x += v1[0]; acc.y += v1[1]; acc.z += v1[2]; acc.w += v1[3];
                    acc2.x += v1[0] * f1; acc2.y += v1[1] * f1; acc2.z += v1[2] * f1; acc2.w += v1[3] * f1;
                    acc.x += v2[0]; acc.y += v2[1]; acc.z += v2[2]; acc.w += v2[3];
                    acc2.x += v2[0] * f2; acc2.y += v2[1] * f2; acc2.z += v2[2] * f2; acc2.w += v2[3] * f2;
                    acc.x += v3[0]; acc.y += v3[1]; acc.z += v3[2]; acc.w += v3[3];
                    acc2.x += v3[0] * f3; acc2.y += v3[1] * f3; acc2.z += v3[2] * f3; acc2.w += v3[3] * f3;
                    acc.x += v4[0]; acc.y += v4[1]; acc.z += v4[2]; acc.w += v4[3];
                    acc2.x += v4[0] * f4_; acc2.y += v4[1] * f4_; acc2.z += v4[2] * f4_; acc2.w += v4[3] * f4_;
                    acc.x += v5[0]; acc.y += v5[1]; acc.z += v5[2]; acc.w += v5[3];
                    acc2.x += v5[0] * f5; acc2.y += v5[1] * f5; acc2.z += v5[2] * f5; acc2.w += v5[3] * f5;
                    acc.x += v6[0]; acc.y += v6[1]; acc.z += v6[2]; acc.w += v6[3];
                    acc2.x += v6[0] * f6; acc2.y += v6[1] * f6; acc2.z += v6[2] * f6; acc2.w += v6[3] * f6;
                    acc.x += v7[0]; acc.y += v7[1]; acc.z += v7[2]; acc.w += v7[3];
                    acc2.x += v7[0] * f7; acc2.y += v7[1] * f7; acc2.z += v7[2] * f7; acc2.w += v7[3] * f7;
                }
                for (; j < m; j++) {
                    int i0 = __shfl(lid, j);
                    float f0 = __shfl(fvl, j);
                    float4 v0 = ((const float4*)(feat + (long)i0 * D))[t];
                    acc.x += v0.x; acc.y += v0.y; acc.z += v0.z; acc.w += v0.w;
                    acc2.x += v0.x * f0; acc2.y += v0.y * f0; acc2.z += v0.z * f0; acc2.w += v0.w * f0;
                }
            }
            float inv = 1.0f / (float)n;
            o0 = acc.x * inv; o1 = acc.y * inv; o2 = acc.z * inv; o3 = acc.w * inv;
        }
        float* dst = ftab + (long)c * D + t * 4;
        dst[0] = o0; dst[1] = o1; dst[2] = o2; dst[3] = o3;
        if (n > 0) ((float4*)(gsum + (long)c * D))[t] = acc2;
        float ss = o0 * o0 + o1 * o1 + o2 * o2 + o3 * o3;
        ss = block_sum(ss, red);
        if (t == 0) norms[c] = sqrtf(ss);
    } else {
        int c = blockIdx.x - C;
        int n = counts[c];
        int nv = C2 >> 2;                           // 250
        if (n == 0) {
            for (int d = t; d < C2; d += 256) ltab[(long)c * C2 + d] = linit[(long)c * C2 + d];
            return;
        }
        int tc = min(t, nv - 1);
        int o = offsets[c];
        float4 acc = {0.f, 0.f, 0.f, 0.f};
        for (int base = 0; base < n; base += 64) {
            int m = min(64, n - base);
            int lid = idx[o + base + min(lane, m - 1)];
            int m8 = m & ~7;
            int j = 0;
            for (; j < m8; j += 8) {
                int i0 = __shfl(lid, j),     i1 = __shfl(lid, j + 1);
                int i2 = __shfl(lid, j + 2), i3 = __shfl(lid, j + 3);
                int i4 = __shfl(lid, j + 4), i5 = __shfl(lid, j + 5);
                int i6 = __shfl(lid, j + 6), i7 = __shfl(lid, j + 7);
                f32x4 v0 = gload4(logits + (long)i0 * C2 + tc * 4);
                f32x4 v1 = gload4(logits + (long)i1 * C2 + tc * 4);
                f32x4 v2 = gload4(logits + (long)i2 * C2 + tc * 4);
                f32x4 v3 = gload4(logits + (long)i3 * C2 + tc * 4);
                f32x4 v4 = gload4(logits + (long)i4 * C2 + tc * 4);
                f32x4 v5 = gload4(logits + (long)i5 * C2 + tc * 4);
                f32x4 v6 = gload4(logits + (long)i6 * C2 + tc * 4);
                f32x4 v7 = gload4(logits + (long)i7 * C2 + tc * 4);
                asm volatile("s_waitcnt vmcnt(0)"
                             : "+v"(v0), "+v"(v1), "+v"(v2), "+v"(v3),
                               "+v"(v4), "+v"(v5), "+v"(v6), "+v"(v7));
                __builtin_amdgcn_sched_barrier(0);
                acc.x += v0[0]; acc.y += v0[1]; acc.z += v0[2]; acc.w += v0[3];
                acc.x += v1[0]; acc.y += v1[1]; acc.z += v1[2]; acc.w += v1[3];
                acc.x += v2[0]; acc.y += v2[1]; acc.z += v2[2]; acc.w += v2[3];
                acc.x += v3[0]; acc.y += v3[1]; acc.z += v3[2]; acc.w += v3[3];
                acc.x += v4[0]; acc.y += v4[1]; acc.z += v4[2]; acc.w += v4[3];
                acc.x += v5[0]; acc.y += v5[1]; acc.z += v5[2]; acc.w += v5[3];
                acc.x += v6[0]; acc.y += v6[1]; acc.z += v6[2]; acc.w += v6[3];
                acc.x += v7[0]; acc.y += v7[1]; acc.z += v7[2]; acc.w += v7[3];
            }
            for (; j < m; j++) {
                int i0 = __shfl(lid, j);
                float4 v0 = *(const float4*)(logits + (long)i0 * C2 + tc * 4);
                acc.x += v0.x; acc.y += v0.y; acc.z += v0.z; acc.w += v0.w;
            }
        }
        if (t < nv) {
            float inv = 1.0f / (float)n;
            float* dst = ltab + (long)c * C2 + t * 4;
            dst[0] = acc.x * inv;
            dst[1] = acc.y * inv;
            dst[2] = acc.z * inv;
            dst[3] = acc.w * inv;
        }
    }
}

// Triangular raw-dot GEMM via bf16 MFMA: one block per upper-tri 64x64 tile.
__global__ __launch_bounds__(1024) void k_gemm(const float* A, float* S,
                                               int C, int D, int NT) {
    __shared__ __align__(16) unsigned short As[2][64][40];
    __shared__ __align__(16) unsigned short Bs[2][64][40];
    __shared__ __align__(16) float racc[64 * 68];
    int t = threadIdx.x;

    int q = blockIdx.x, ti = 0;
    while (q >= NT - ti) { q -= NT - ti; ti++; }
    int tj = ti + q;
    int rb = ti * 64, cb = tj * 64;

    int srow = t >> 4;
    int skq = (t & 15) * 2;
    int ga = rb + srow, gb = cb + srow;
    bool okA = ga < C, okB = gb < C;
    const float* arow = A + (long)ga * D;
    const float* brow = A + (long)gb * D;

    int w = t >> 6, wr = w >> 2, wc = w & 3;
    int l = t & 63, fr = l & 15, fb = l >> 4;
    int arl = wr * 16 + fr, brl = wc * 16 + fr, koff = fb * 8;

    {
        float2 z2 = {0.f, 0.f};
        float2 pa = okA ? *(const float2*)(arow + skq) : z2;
        float2 pb = okB ? *(const float2*)(brow + skq) : z2;
        As[0][srow][skq] = f2bf(pa.x); As[0][srow][skq + 1] = f2bf(pa.y);
        Bs[0][srow][skq] = f2bf(pb.x); Bs[0][srow][skq + 1] = f2bf(pb.y);
    }
    __syncthreads();

    f32x4 acc = {0.f, 0.f, 0.f, 0.f};
    int nsteps = D >> 5;               // 32
    for (int step = 0; step < nsteps; step++) {
        int cur = step & 1;
        float2 pa, pb;
        if (step < nsteps - 1) {
            int k0n = (step + 1) * 32;
            float2 z2 = {0.f, 0.f};
            pa = okA ? *(const float2*)(arow + k0n + skq) : z2;
            pb = okB ? *(const float2*)(brow + k0n + skq) : z2;
        }
        short8v af = *reinterpret_cast<const short8v*>(&As[cur][arl][koff]);
        short8v bf = *reinterpret_cast<const short8v*>(&Bs[cur][brl][koff]);
        acc = __builtin_amdgcn_mfma_f32_16x16x32_bf16(af, bf, acc, 0, 0, 0);
        if (step < nsteps - 1) {
            int nb = cur ^ 1;
            As[nb][srow][skq] = f2bf(pa.x); As[nb][srow][skq + 1] = f2bf(pa.y);
            Bs[nb][srow][skq] = f2bf(pb.x); Bs[nb][srow][skq + 1] = f2bf(pb.y);
        }
        __syncthreads();
    }

#pragma unroll
    for (int r = 0; r < 4; r++)
        racc[(wr * 16 + fb * 4 + r) * 68 + wc * 16 + fr] = acc[r];
    __syncthreads();

    int r0 = t >> 4;
    int cbl = (t & 15) * 4;
    int gr = rb + r0;
    bool edge = (tj == NT - 1);
    if (gr < C) {
        float4 v4 = *reinterpret_cast<const float4*>(&racc[r0 * 68 + cbl]);
        float v[4] = {v4.x, v4.y, v4.z, v4.w};
        float* dst = S + (long)gr * C + cb + cbl;
        if (!edge) {
            *reinterpret_cast<float2*>(dst) = make_float2(v[0], v[1]);
            *reinterpret_cast<float2*>(dst + 2) = make_float2(v[2], v[3]);
        } else {
#pragma unroll
            for (int m = 0; m < 4; m++)
                if (cb + cbl + m < C) dst[m] = v[m];
        }
    }
    if (ti != tj) {
        int cc0 = cb + r0;
        if (cc0 < C) {
            float wv[4];
#pragma unroll
            for (int m = 0; m < 4; m++) wv[m] = racc[(cbl + m) * 68 + r0];
            float* dst = S + (long)cc0 * C + rb + cbl;
            *reinterpret_cast<float2*>(dst) = make_float2(wv[0], wv[1]);
            *reinterpret_cast<float2*>(dst + 2) = make_float2(wv[2], wv[3]);
        }
    }
}

// per-row: best/argmax (excl diag) of cos values + global min/max (incl diag).
__global__ void k_rowmax(const float* S, const float* norms, unsigned* minmax,
                         float* simraw, int* simcls, int C) {
    __shared__ float invn[1024];
    __shared__ float rv[256], rmn[256], rmx[256];
    __shared__ int ri[256];
    int c = blockIdx.x, t = threadIdx.x;
    for (int j = t; j < C; j += 256) invn[j] = 1.f / norms[j];
    __syncthreads();
    float inc = invn[c];
    float best = -INFINITY, lmin = INFINITY, lmax = -INFINITY;
    int bi = 0x7FFFFFFF;
    long rowo = (long)c * C;
    for (int j = t; j < C; j += 256) {
        float v = S[rowo + j] * inc * invn[j];
        lmin = fminf(lmin, v);
        lmax = fmaxf(lmax, v);
        if (j != c && v > best) { best = v; bi = j; }
    }
    rv[t] = best; ri[t] = bi; rmn[t] = lmin; rmx[t] = lmax;
    __syncthreads();
    for (int k = 128; k > 0; k >>= 1) {
        if (t < k) {
            if (rv[t + k] > rv[t] || (rv[t + k] == rv[t] && ri[t + k] < ri[t])) {
                rv[t] = rv[t + k];
                ri[t] = ri[t + k];
            }
            rmn[t] = fminf(rmn[t], rmn[t + k]);
            rmx[t] = fmaxf(rmx[t], rmx[t + k]);
        }
        __syncthreads();
    }
    if (t == 0) {
        simraw[c] = rv[0];
        simcls[c] = ri[0];
        atomicMin(&minmax[0], fenc(rmn[0]));
        atomicMax(&minmax[1], fenc(rmx[0]));
    }
}

// Per-class losses via factored identities:
//  cpf[c] = n_c - dot(g_c,u_c)/max(|u_c|,eps) + sv_c*dot(g_c,v_c)/max(|v_c|,eps)
//  cpk[c] = LSE_c - n_c*lse(ltab_c)
__global__ __launch_bounds__(256) void k_closs(const float* gsum, const float* ftab,
                                               const float* norms, const int* counts,
                                               const int* offsets, const int* idx,
                                               const float* lse, const float* ltab,
                                               const unsigned* minmax, const float* simraw,
                                               const int* simcls,
                                               float* cpf, float* cpk,
                                               int C, int D, int C2) {
    __shared__ float red[256];
    int c = blockIdx.x, t = threadIdx.x;
    int n = counts[c];
    if (n == 0) {
        if (t == 0) { cpf[c] = 0.f; cpk[c] = 0.f; }
        return;
    }
    int sc = simcls[c];
    float4 g4 = ((const float4*)(gsum + (long)c * D))[t];
    const float* u = ftab + (long)c * D + t * 4;
    const float* v = ftab + (long)sc * D + t * 4;
    float d1 = g4.x * u[0] + g4.y * u[1] + g4.z * u[2] + g4.w * u[3];
    float d2 = g4.x * v[0] + g4.y * v[1] + g4.z * v[2] + g4.w * v[3];
    d1 = block_sum(d1, red);
    d2 = block_sum(d2, red);
    float ta[4];
    float lm = -INFINITY;
#pragma unroll
    for (int k = 0; k < 4; k++) {
        int j = t + k * 256;
        if (j < C2) { ta[k] = ltab[(long)c * C2 + j]; lm = fmaxf(lm, ta[k]); }
        else ta[k] = -INFINITY;
    }
    lm = block_max(lm, red);
    float se = 0.f;
#pragma unroll
    for (int k = 0; k < 4; k++)
        if (ta[k] != -INFINITY) se += __expf(ta[k] - lm);
    se = block_sum(se, red);
    float ls = 0.f;
    int o = offsets[c];
    for (int i = t; i < n; i += 256) ls += lse[idx[o + i]];
    ls = block_sum(ls, red);
    if (t == 0) {
        float cmin = fdec(minmax[0]);
        float cmax = fdec(minmax[1]);
        float sv = (simraw[c] - cmin) / (cmax - cmin);
        float nu = fmaxf(norms[c], EPS);
        float nv = fmaxf(norms[sc], EPS);
        cpf[c] = (float)n - d1 / nu + sv * d2 / nv;
        cpk[c] = ls - (float)n * (lm + __logf(se));
    }
}

__global__ void k_final(const float* cpf, const float* cpk, float* out, int C) {
    __shared__ float red[256];
    float a = 0.f;
    for (int i = threadIdx.x; i < C; i += 256) a += cpf[i];
    a = block_sum(a, red);
    float b = 0.f;
    for (int i = threadIdx.x; i < C; i += 256) b += cpk[i];
    b = block_sum(b, red);
    if (threadIdx.x == 0) {
        out[0] = a;
        out[1] = b;
    }
}

extern "C" void kernel_launch(void* const* d_in, const int* in_sizes, int n_in,
                              void* d_out, int out_size, void* d_ws, size_t ws_size,
                              hipStream_t stream) {
    const float* feature = (const float*)d_in[0];
    const float* logits  = (const float*)d_in[1];
    const int*   targets = (const int*)d_in[2];
    const float* finit   = (const float*)d_in[3];
    const float* linit   = (const float*)d_in[4];

    const int B = in_sizes[2];                 // 16384
    const int D = in_sizes[0] / B;             // 1024
    const int C = in_sizes[3] / D;             // 1000

    float* out = (float*)d_out;
    float* ftab = out + 2;                     // [C, D]
    float* ltab = out + 2 + (long)C * D;       // [C, C]

    const int G = 64;                          // histogram groups
    const int NT = (C + 63) / 64;              // 16 tiles per dim
    const int NTRI = NT * (NT + 1) / 2;        // 136 triangular tiles

    char* ws = (char*)d_ws;
    int*      counts   = (int*)(ws + 0);          // 4KB
    int*      offsets  = (int*)(ws + 4096);       // 4KB
    int*      idx      = (int*)(ws + 12288);      // 64KB
    float*    norms    = (float*)(ws + 77824);    // 4KB
    float*    simraw   = (float*)(ws + 81920);    // 4KB
    int*      simcls   = (int*)(ws + 86016);      // 4KB
    unsigned* minmax   = (unsigned*)(ws + 90112); // 8B
    float*    cpf      = (float*)(ws + 90368);    // 4KB
    float*    cpk      = (float*)(ws + 94464);    // 4KB
    float*    fnorminv = (float*)(ws + 98560);    // 64KB
    float*    lse      = (float*)(ws + 164096);   // 64KB
    float*    Sws      = (float*)(ws + 262144);   // C*C floats = 4MB
    float*    gsum     = (float*)(ws + 262144 + (size_t)C * C * sizeof(float)); // C*D

    float* S = Sws;                            // ws_size >= 12.25MB proven (round 12)

    // gh scratch lives in the (not-yet-written) ltab output region
    int* gh = (int*)ltab;

    // prepass: histogram + persistent-wave streaming (1/|f| and lse)
    k_pre<<<64 + 2048, 256, 0, stream>>>(targets, gh, feature, fnorminv,
                                         logits, lse, B, D, C);
    k_bases<<<1, 1024, 0, stream>>>(gh, counts, offsets, minmax, G, C);
    k_rank_scatter<<<G, 256, 0, stream>>>(targets, offsets, gh, idx, B);

    // both gathers in one dispatch; feature path also accumulates g = sum(f/|f|)
    k_tables<<<2 * C, 256, 0, stream>>>(feature, finit, logits, linit,
                                        counts, offsets, idx, fnorminv,
                                        ftab, ltab, norms, gsum, C, D, C);

    k_gemm<<<NTRI, 1024, 0, stream>>>(ftab, S, C, D, NT);
    k_rowmax<<<C, 256, 0, stream>>>(S, norms, minmax, simraw, simcls, C);
    k_closs<<<C, 256, 0, stream>>>(gsum, ftab, norms, counts, offsets, idx,
                                   lse, ltab, minmax, simraw, simcls, cpf, cpk, C, D, C);
    k_final<<<1, 256, 0, stream>>>(cpf, cpk, out, C);
}

// Round 31
// 127.943 us; speedup vs baseline: 1.0723x; 1.0412x over previous
//
#include <hip/hip_runtime.h>
#include <hip/hip_bf16.h>
#include <math.h>

#define EPS 1e-8f

typedef __attribute__((ext_vector_type(8))) short short8v;
typedef __attribute__((ext_vector_type(4))) float f32x4;

// ---------- helpers ----------
__device__ __forceinline__ unsigned fenc(float f) {
    unsigned u = __float_as_uint(f);
    return (u & 0x80000000u) ? ~u : (u | 0x80000000u);
}
__device__ __forceinline__ float fdec(unsigned e) {
    unsigned u = (e & 0x80000000u) ? (e & 0x7FFFFFFFu) : ~e;
    return __uint_as_float(u);
}
__device__ __forceinline__ unsigned short f2bf(float f) {   // RNE f32 -> bf16
    unsigned u = __float_as_uint(f);
    u += 0x7FFFu + ((u >> 16) & 1u);
    return (unsigned short)(u >> 16);
}

// async global load: compiler cannot serialize volatile asm loads
__device__ __forceinline__ f32x4 gload4(const float* p) {
    f32x4 r;
    asm volatile("global_load_dwordx4 %0, %1, off" : "=v"(r) : "v"(p));
    return r;
}

__device__ __forceinline__ float block_sum(float v, float* red) {
    red[threadIdx.x] = v;
    __syncthreads();
    for (int k = 128; k > 0; k >>= 1) {
        if (threadIdx.x < k) red[threadIdx.x] += red[threadIdx.x + k];
        __syncthreads();
    }
    float r = red[0];
    __syncthreads();
    return r;
}
__device__ __forceinline__ float block_max(float v, float* red) {
    red[threadIdx.x] = v;
    __syncthreads();
    for (int k = 128; k > 0; k >>= 1) {
        if (threadIdx.x < k) red[threadIdx.x] = fmaxf(red[threadIdx.x], red[threadIdx.x + k]);
        __syncthreads();
    }
    float r = red[0];
    __syncthreads();
    return r;
}

// ---------- kernels ----------
// histogram only (per-row norm/lse now fused into k_tables)
__global__ __launch_bounds__(256) void k_hist(const int* tgt, int* gh, int B) {
    __shared__ int lh[1024];
    int g = blockIdx.x, t = threadIdx.x;
    lh[t] = 0; lh[t + 256] = 0; lh[t + 512] = 0; lh[t + 768] = 0;
    __syncthreads();
    int i = g * 256 + t;
    if (i < B) atomicAdd(&lh[tgt[i]], 1);
    __syncthreads();
    int* dst = gh + g * 1024;
    dst[t] = lh[t]; dst[t + 256] = lh[t + 256];
    dst[t + 512] = lh[t + 512]; dst[t + 768] = lh[t + 768];
}

__global__ void k_bases(int* gh, int* counts, int* offsets, unsigned* minmax, int G, int C) {
    __shared__ int buf[1024];
    int c = threadIdx.x;
    if (c == 0) { minmax[0] = 0xFFFFFFFFu; minmax[1] = 0u; }
    int run = 0;
#pragma unroll 16
    for (int g = 0; g < G; g++) {
        int v = gh[g * 1024 + c];
        gh[g * 1024 + c] = run;
        run += v;
    }
    if (c < C) counts[c] = run;
    int v0 = (c < C) ? run : 0;
    buf[c] = v0;
    __syncthreads();
    for (int off = 1; off < 1024; off <<= 1) {
        int v = (c >= off) ? buf[c - off] : 0;
        __syncthreads();
        buf[c] += v;
        __syncthreads();
    }
    if (c < C) offsets[c] = buf[c] - v0;
}

__global__ void k_rank_scatter(const int* tgt, const int* offsets, const int* gh,
                               int* idx, int B) {
    __shared__ int lt[256];
    int g = blockIdx.x, t = threadIdx.x;
    int i = g * 256 + t;
    int my = (i < B) ? tgt[i] : -1;
    lt[t] = my;
    __syncthreads();
    if (i < B) {
        int rank = 0;
        for (int j = 0; j < t; j++) rank += (lt[j] == my);
        idx[offsets[my] + gh[g * 1024 + my] + rank] = i;
    }
}

// FUSED table build + per-row reductions (single full-input pass):
//  blocks [0,C): feature table + per-row ||f|| (in-gather) + g = sum f/|f| + norms
//  blocks [C,2C): logit table + per-row lse (in-gather) + cpk[c] = SUMlse - n*lse(mean)
// Loads via asm batch-8 + one vmcnt(0). Ascending accumulation order (deterministic).
__global__ __launch_bounds__(256) void k_tables(const float* feat, const float* finit,
                                                const float* logits, const float* linit,
                                                const int* counts, const int* offsets,
                                                const int* idx,
                                                float* ftab, float* ltab, float* norms,
                                                float* gsum, float* cpk,
                                                int C, int D, int C2) {
    __shared__ float red[256];
    __shared__ float wsum[4][8];
    int t = threadIdx.x;
    int lane = t & 63;
    int wid = t >> 6;
    if ((int)blockIdx.x < C) {
        // ---------------- feature path ----------------
        int c = blockIdx.x;
        int n = counts[c];
        float o0, o1, o2, o3;
        float4 acc2 = {0.f, 0.f, 0.f, 0.f};
        if (n == 0) {
            float4 v = ((const float4*)(finit + (long)c * D))[t];
            o0 = v.x; o1 = v.y; o2 = v.z; o3 = v.w;
        } else {
            int o = offsets[c];
            float4 acc = {0.f, 0.f, 0.f, 0.f};
            for (int base = 0; base < n; base += 64) {
                int m = min(64, n - base);
                int lid = idx[o + base + min(lane, m - 1)];
                int m8 = m & ~7;
                int j = 0;
                for (; j < m8; j += 8) {
                    int i0 = __shfl(lid, j),     i1 = __shfl(lid, j + 1);
                    int i2 = __shfl(lid, j + 2), i3 = __shfl(lid, j + 3);
                    int i4 = __shfl(lid, j + 4), i5 = __shfl(lid, j + 5);
                    int i6 = __shfl(lid, j + 6), i7 = __shfl(lid, j + 7);
                    f32x4 v0 = gload4(feat + (long)i0 * D + t * 4);
                    f32x4 v1 = gload4(feat + (long)i1 * D + t * 4);
                    f32x4 v2 = gload4(feat + (long)i2 * D + t * 4);
                    f32x4 v3 = gload4(feat + (long)i3 * D + t * 4);
                    f32x4 v4 = gload4(feat + (long)i4 * D + t * 4);
                    f32x4 v5 = gload4(feat + (long)i5 * D + t * 4);
                    f32x4 v6 = gload4(feat + (long)i6 * D + t * 4);
                    f32x4 v7 = gload4(feat + (long)i7 * D + t * 4);
                    asm volatile("s_waitcnt vmcnt(0)"
                                 : "+v"(v0), "+v"(v1), "+v"(v2), "+v"(v3),
                                   "+v"(v4), "+v"(v5), "+v"(v6), "+v"(v7));
                    __builtin_amdgcn_sched_barrier(0);
                    // per-row squared-norm partials
                    float p0 = v0[0]*v0[0]+v0[1]*v0[1]+v0[2]*v0[2]+v0[3]*v0[3];
                    float p1 = v1[0]*v1[0]+v1[1]*v1[1]+v1[2]*v1[2]+v1[3]*v1[3];
                    float p2 = v2[0]*v2[0]+v2[1]*v2[1]+v2[2]*v2[2]+v2[3]*v2[3];
                    float p3 = v3[0]*v3[0]+v3[1]*v3[1]+v3[2]*v3[2]+v3[3]*v3[3];
                    float p4 = v4[0]*v4[0]+v4[1]*v4[1]+v4[2]*v4[2]+v4[3]*v4[3];
                    float p5 = v5[0]*v5[0]+v5[1]*v5[1]+v5[2]*v5[2]+v5[3]*v5[3];
                    float p6 = v6[0]*v6[0]+v6[1]*v6[1]+v6[2]*v6[2]+v6[3]*v6[3];
                    float p7 = v7[0]*v7[0]+v7[1]*v7[1]+v7[2]*v7[2]+v7[3]*v7[3];
#pragma unroll
                    for (int off = 32; off > 0; off >>= 1) {
                        p0 += __shfl_xor(p0, off); p1 += __shfl_xor(p1, off);
                        p2 += __shfl_xor(p2, off); p3 += __shfl_xor(p3, off);
                        p4 += __shfl_xor(p4, off); p5 += __shfl_xor(p5, off);
                        p6 += __shfl_xor(p6, off); p7 += __shfl_xor(p7, off);
                    }
                    if (lane == 0) {
                        wsum[wid][0] = p0; wsum[wid][1] = p1; wsum[wid][2] = p2; wsum[wid][3] = p3;
                        wsum[wid][4] = p4; wsum[wid][5] = p5; wsum[wid][6] = p6; wsum[wid][7] = p7;
                    }
                    __syncthreads();
                    float s0 = wsum[0][0]+wsum[1][0]+wsum[2][0]+wsum[3][0];
                    float s1 = wsum[0][1]+wsum[1][1]+wsum[2][1]+wsum[3][1];
                    float s2 = wsum[0][2]+wsum[1][2]+wsum[2][2]+wsum[3][2];
                    float s3 = wsum[0][3]+wsum[1][3]+wsum[2][3]+wsum[3][3];
                    float s4 = wsum[0][4]+wsum[1][4]+wsum[2][4]+wsum[3][4];
                    float s5 = wsum[0][5]+wsum[1][5]+wsum[2][5]+wsum[3][5];
                    float s6 = wsum[0][6]+wsum[1][6]+wsum[2][6]+wsum[3][6];
                    float s7 = wsum[0][7]+wsum[1][7]+wsum[2][7]+wsum[3][7];
                    __syncthreads();
                    float fn0 = 1.f / fmaxf(sqrtf(s0), EPS);
                    float fn1 = 1.f / fmaxf(sqrtf(s1), EPS);
                    float fn2 = 1.f / fmaxf(sqrtf(s2), EPS);
                    float fn3 = 1.f / fmaxf(sqrtf(s3), EPS);
                    float fn4 = 1.f / fmaxf(sqrtf(s4), EPS);
                    float fn5 = 1.f / fmaxf(sqrtf(s5), EPS);
                    float fn6 = 1.f / fmaxf(sqrtf(s6), EPS);
                    float fn7 = 1.f / fmaxf(sqrtf(s7), EPS);
                    acc.x += v0[0]; acc.y += v0[1]; acc.z += v0[2]; acc.w += v0[3];
                    acc2.x += v0[0]*fn0; acc2.y += v0[1]*fn0; acc2.z += v0[2]*fn0; acc2.w += v0[3]*fn0;
                    acc.x += v1[0]; acc.y += v1[1]; acc.z += v1[2]; acc.w += v1[3];
                    acc2.x += v1[0]*fn1; acc2.y += v1[1]*fn1; acc2.z += v1[2]*fn1; acc2.w += v1[3]*fn1;
                    acc.x += v2[0]; acc.y += v2[1]; acc.z += v2[2]; acc.w += v2[3];
                    acc2.x += v2[0]*fn2; acc2.y += v2[1]*fn2; acc2.z += v2[2]*fn2; acc2.w += v2[3]*fn2;
                    acc.x += v3[0]; acc.y += v3[1]; acc.z += v3[2]; acc.w += v3[3];
                    acc2.x += v3[0]*fn3; acc2.y += v3[1]*fn3; acc2.z += v3[2]*fn3; acc2.w += v3[3]*fn3;
                    acc.x += v4[0]; acc.y += v4[1]; acc.z += v4[2]; acc.w += v4[3];
                    acc2.x += v4[0]*fn4; acc2.y += v4[1]*fn4; acc2.z += v4[2]*fn4; acc2.w += v4[3]*fn4;
                    acc.x += v5[0]; acc.y += v5[1]; acc.z += v5[2]; acc.w += v5[3];
                    acc2.x += v5[0]*fn5; acc2.y += v5[1]*fn5; acc2.z += v5[2]*fn5; acc2.w += v5[3]*fn5;
                    acc.x += v6[0]; acc.y += v6[1]; acc.z += v6[2]; acc.w += v6[3];
                    acc2.x += v6[0]*fn6; acc2.y += v6[1]*fn6; acc2.z += v6[2]*fn6; acc2.w += v6[3]*fn6;
                    acc.x += v7[0]; acc.y += v7[1]; acc.z += v7[2]; acc.w += v7[3];
                    acc2.x += v7[0]*fn7; acc2.y += v7[1]*fn7; acc2.z += v7[2]*fn7; acc2.w += v7[3]*fn7;
                }
                for (; j < m; j++) {
                    int i0 = __shfl(lid, j);
                    float4 v = ((const float4*)(feat + (long)i0 * D))[t];
                    float p = v.x*v.x + v.y*v.y + v.z*v.z + v.w*v.w;
#pragma unroll
                    for (int off = 32; off > 0; off >>= 1) p += __shfl_xor(p, off);
                    if (lane == 0) wsum[wid][0] = p;
                    __syncthreads();
                    float ss = wsum[0][0]+wsum[1][0]+wsum[2][0]+wsum[3][0];
                    __syncthreads();
                    float fn = 1.f / fmaxf(sqrtf(ss), EPS);
                    acc.x += v.x; acc.y += v.y; acc.z += v.z; acc.w += v.w;
                    acc2.x += v.x*fn; acc2.y += v.y*fn; acc2.z += v.z*fn; acc2.w += v.w*fn;
                }
            }
            float inv = 1.0f / (float)n;
            o0 = acc.x * inv; o1 = acc.y * inv; o2 = acc.z * inv; o3 = acc.w * inv;
        }
        float* dst = ftab + (long)c * D + t * 4;
        dst[0] = o0; dst[1] = o1; dst[2] = o2; dst[3] = o3;
        if (n > 0) ((float4*)(gsum + (long)c * D))[t] = acc2;
        float ss = o0 * o0 + o1 * o1 + o2 * o2 + o3 * o3;
        ss = block_sum(ss, red);
        if (t == 0) norms[c] = sqrtf(ss);
    } else {
        // ---------------- logits path ----------------
        int c = blockIdx.x - C;
        int n = counts[c];
        int nv = C2 >> 2;                           // 250
        if (n == 0) {
            for (int d = t; d < C2; d += 256) ltab[(long)c * C2 + d] = linit[(long)c * C2 + d];
            if (t == 0) cpk[c] = 0.f;
            return;
        }
        bool tval = t < nv;
        int tc = min(t, nv - 1);                    // clamped -> unconditional loads
        int o = offsets[c];
        float4 acc = {0.f, 0.f, 0.f, 0.f};
        float lsesum = 0.f;
        for (int base = 0; base < n; base += 64) {
            int m = min(64, n - base);
            int lid = idx[o + base + min(lane, m - 1)];
            int m8 = m & ~7;
            int j = 0;
            for (; j < m8; j += 8) {
                int i0 = __shfl(lid, j),     i1 = __shfl(lid, j + 1);
                int i2 = __shfl(lid, j + 2), i3 = __shfl(lid, j + 3);
                int i4 = __shfl(lid, j + 4), i5 = __shfl(lid, j + 5);
                int i6 = __shfl(lid, j + 6), i7 = __shfl(lid, j + 7);
                f32x4 v0 = gload4(logits + (long)i0 * C2 + tc * 4);
                f32x4 v1 = gload4(logits + (long)i1 * C2 + tc * 4);
                f32x4 v2 = gload4(logits + (long)i2 * C2 + tc * 4);
                f32x4 v3 = gload4(logits + (long)i3 * C2 + tc * 4);
                f32x4 v4 = gload4(logits + (long)i4 * C2 + tc * 4);
                f32x4 v5 = gload4(logits + (long)i5 * C2 + tc * 4);
                f32x4 v6 = gload4(logits + (long)i6 * C2 + tc * 4);
                f32x4 v7 = gload4(logits + (long)i7 * C2 + tc * 4);
                asm volatile("s_waitcnt vmcnt(0)"
                             : "+v"(v0), "+v"(v1), "+v"(v2), "+v"(v3),
                               "+v"(v4), "+v"(v5), "+v"(v6), "+v"(v7));
                __builtin_amdgcn_sched_barrier(0);
                // per-row max
                float q0 = tval ? fmaxf(fmaxf(v0[0],v0[1]),fmaxf(v0[2],v0[3])) : -INFINITY;
                float q1 = tval ? fmaxf(fmaxf(v1[0],v1[1]),fmaxf(v1[2],v1[3])) : -INFINITY;
                float q2 = tval ? fmaxf(fmaxf(v2[0],v2[1]),fmaxf(v2[2],v2[3])) : -INFINITY;
                float q3 = tval ? fmaxf(fmaxf(v3[0],v3[1]),fmaxf(v3[2],v3[3])) : -INFINITY;
                float q4 = tval ? fmaxf(fmaxf(v4[0],v4[1]),fmaxf(v4[2],v4[3])) : -INFINITY;
                float q5 = tval ? fmaxf(fmaxf(v5[0],v5[1]),fmaxf(v5[2],v5[3])) : -INFINITY;
                float q6 = tval ? fmaxf(fmaxf(v6[0],v6[1]),fmaxf(v6[2],v6[3])) : -INFINITY;
                float q7 = tval ? fmaxf(fmaxf(v7[0],v7[1]),fmaxf(v7[2],v7[3])) : -INFINITY;
#pragma unroll
                for (int off = 32; off > 0; off >>= 1) {
                    q0 = fmaxf(q0, __shfl_xor(q0, off)); q1 = fmaxf(q1, __shfl_xor(q1, off));
                    q2 = fmaxf(q2, __shfl_xor(q2, off)); q3 = fmaxf(q3, __shfl_xor(q3, off));
                    q4 = fmaxf(q4, __shfl_xor(q4, off)); q5 = fmaxf(q5, __shfl_xor(q5, off));
                    q6 = fmaxf(q6, __shfl_xor(q6, off)); q7 = fmaxf(q7, __shfl_xor(q7, off));
                }
                if (lane == 0) {
                    wsum[wid][0] = q0; wsum[wid][1] = q1; wsum[wid][2] = q2; wsum[wid][3] = q3;
                    wsum[wid][4] = q4; wsum[wid][5] = q5; wsum[wid][6] = q6; wsum[wid][7] = q7;
                }
                __syncthreads();
                float lm0 = fmaxf(fmaxf(wsum[0][0],wsum[1][0]),fmaxf(wsum[2][0],wsum[3][0]));
                float lm1 = fmaxf(fmaxf(wsum[0][1],wsum[1][1]),fmaxf(wsum[2][1],wsum[3][1]));
                float lm2 = fmaxf(fmaxf(wsum[0][2],wsum[1][2]),fmaxf(wsum[2][2],wsum[3][2]));
                float lm3 = fmaxf(fmaxf(wsum[0][3],wsum[1][3]),fmaxf(wsum[2][3],wsum[3][3]));
                float lm4 = fmaxf(fmaxf(wsum[0][4],wsum[1][4]),fmaxf(wsum[2][4],wsum[3][4]));
                float lm5 = fmaxf(fmaxf(wsum[0][5],wsum[1][5]),fmaxf(wsum[2][5],wsum[3][5]));
                float lm6 = fmaxf(fmaxf(wsum[0][6],wsum[1][6]),fmaxf(wsum[2][6],wsum[3][6]));
                float lm7 = fmaxf(fmaxf(wsum[0][7],wsum[1][7]),fmaxf(wsum[2][7],wsum[3][7]));
                __syncthreads();
                // per-row sum of exp
                float e0 = tval ? (__expf(v0[0]-lm0)+__expf(v0[1]-lm0)+__expf(v0[2]-lm0)+__expf(v0[3]-lm0)) : 0.f;
                float e1 = tval ? (__expf(v1[0]-lm1)+__expf(v1[1]-lm1)+__expf(v1[2]-lm1)+__expf(v1[3]-lm1)) : 0.f;
                float e2 = tval ? (__expf(v2[0]-lm2)+__expf(v2[1]-lm2)+__expf(v2[2]-lm2)+__expf(v2[3]-lm2)) : 0.f;
                float e3 = tval ? (__expf(v3[0]-lm3)+__expf(v3[1]-lm3)+__expf(v3[2]-lm3)+__expf(v3[3]-lm3)) : 0.f;
                float e4 = tval ? (__expf(v4[0]-lm4)+__expf(v4[1]-lm4)+__expf(v4[2]-lm4)+__expf(v4[3]-lm4)) : 0.f;
                float e5 = tval ? (__expf(v5[0]-lm5)+__expf(v5[1]-lm5)+__expf(v5[2]-lm5)+__expf(v5[3]-lm5)) : 0.f;
                float e6 = tval ? (__expf(v6[0]-lm6)+__expf(v6[1]-lm6)+__expf(v6[2]-lm6)+__expf(v6[3]-lm6)) : 0.f;
                float e7 = tval ? (__expf(v7[0]-lm7)+__expf(v7[1]-lm7)+__expf(v7[2]-lm7)+__expf(v7[3]-lm7)) : 0.f;
#pragma unroll
                for (int off = 32; off > 0; off >>= 1) {
                    e0 += __shfl_xor(e0, off); e1 += __shfl_xor(e1, off);
                    e2 += __shfl_xor(e2, off); e3 += __shfl_xor(e3, off);
                    e4 += __shfl_xor(e4, off); e5 += __shfl_xor(e5, off);
                    e6 += __shfl_xor(e6, off); e7 += __shfl_xor(e7, off);
                }
                if (lane == 0) {
                    wsum[wid][0] = e0; wsum[wid][1] = e1; wsum[wid][2] = e2; wsum[wid][3] = e3;
                    wsum[wid][4] = e4; wsum[wid][5] = e5; wsum[wid][6] = e6; wsum[wid][7] = e7;
                }
                __syncthreads();
                float se0 = wsum[0][0]+wsum[1][0]+wsum[2][0]+wsum[3][0];
                float se1 = wsum[0][1]+wsum[1][1]+wsum[2][1]+wsum[3][1];
                float se2 = wsum[0][2]+wsum[1][2]+wsum[2][2]+wsum[3][2];
                float se3 = wsum[0][3]+wsum[1][3]+wsum[2][3]+wsum[3][3];
                float se4 = wsum[0][4]+wsum[1][4]+wsum[2][4]+wsum[3][4];
                float se5 = wsum[0][5]+wsum[1][5]+wsum[2][5]+wsum[3][5];
                float se6 = wsum[0][6]+wsum[1][6]+wsum[2][6]+wsum[3][6];
                float se7 = wsum[0][7]+wsum[1][7]+wsum[2][7]+wsum[3][7];
                __syncthreads();
                lsesum += lm0 + __logf(se0);
                lsesum += lm1 + __logf(se1);
                lsesum += lm2 + __logf(se2);
                lsesum += lm3 + __logf(se3);
                lsesum += lm4 + __logf(se4);
                lsesum += lm5 + __logf(se5);
                lsesum += lm6 + __logf(se6);
                lsesum += lm7 + __logf(se7);
                acc.x += v0[0]; acc.y += v0[1]; acc.z += v0[2]; acc.w += v0[3];
                acc.x += v1[0]; acc.y += v1[1]; acc.z += v1[2]; acc.w += v1[3];
                acc.x += v2[0]; acc.y += v2[1]; acc.z += v2[2]; acc.w += v2[3];
                acc.x += v3[0]; acc.y += v3[1]; acc.z += v3[2]; acc.w += v3[3];
                acc.x += v4[0]; acc.y += v4[1]; acc.z += v4[2]; acc.w += v4[3];
                acc.x += v5[0]; acc.y += v5[1]; acc.z += v5[2]; acc.w += v5[3];
                acc.x += v6[0]; acc.y += v6[1]; acc.z += v6[2]; acc.w += v6[3];
                acc.x += v7[0]; acc.y += v7[1]; acc.z += v7[2]; acc.w += v7[3];
            }
            for (; j < m; j++) {
                int i0 = __shfl(lid, j);
                float4 v = *(const float4*)(logits + (long)i0 * C2 + tc * 4);
                float q = tval ? fmaxf(fmaxf(v.x, v.y), fmaxf(v.z, v.w)) : -INFINITY;
#pragma unroll
                for (int off = 32; off > 0; off >>= 1) q = fmaxf(q, __shfl_xor(q, off));
                if (lane == 0) wsum[wid][0] = q;
                __syncthreads();
                float lm = fmaxf(fmaxf(wsum[0][0],wsum[1][0]),fmaxf(wsum[2][0],wsum[3][0]));
                __syncthreads();
                float e = tval ? (__expf(v.x-lm)+__expf(v.y-lm)+__expf(v.z-lm)+__expf(v.w-lm)) : 0.f;
#pragma unroll
                for (int off = 32; off > 0; off >>= 1) e += __shfl_xor(e, off);
                if (lane == 0) wsum[wid][0] = e;
                __syncthreads();
                float se = wsum[0][0]+wsum[1][0]+wsum[2][0]+wsum[3][0];
                __syncthreads();
                lsesum += lm + __logf(se);
                acc.x += v.x; acc.y += v.y; acc.z += v.z; acc.w += v.w;
            }
        }
        float inv = 1.0f / (float)n;
        float r0 = acc.x * inv, r1 = acc.y * inv, r2 = acc.z * inv, r3 = acc.w * inv;
        if (tval) {
            float* dst = ltab + (long)c * C2 + t * 4;
            dst[0] = r0; dst[1] = r1; dst[2] = r2; dst[3] = r3;
        }
        // lse of the mean row -> cpk
        float qm = tval ? fmaxf(fmaxf(r0, r1), fmaxf(r2, r3)) : -INFINITY;
        qm = block_max(qm, red);
        float em = tval ? (__expf(r0-qm)+__expf(r1-qm)+__expf(r2-qm)+__expf(r3-qm)) : 0.f;
        em = block_sum(em, red);
        if (t == 0) cpk[c] = lsesum - (float)n * (qm + __logf(em));
    }
}

// Triangular raw-dot GEMM via bf16 MFMA: one block per upper-tri 64x64 tile.
__global__ __launch_bounds__(1024) void k_gemm(const float* A, float* S,
                                               int C, int D, int NT) {
    __shared__ __align__(16) unsigned short As[2][64][40];
    __shared__ __align__(16) unsigned short Bs[2][64][40];
    __shared__ __align__(16) float racc[64 * 68];
    int t = threadIdx.x;

    int q = blockIdx.x, ti = 0;
    while (q >= NT - ti) { q -= NT - ti; ti++; }
    int tj = ti + q;
    int rb = ti * 64, cb = tj * 64;

    int srow = t >> 4;
    int skq = (t & 15) * 2;
    int ga = rb + srow, gb = cb + srow;
    bool okA = ga < C, okB = gb < C;
    const float* arow = A + (long)ga * D;
    const float* brow = A + (long)gb * D;

    int w = t >> 6, wr = w >> 2, wc = w & 3;
    int l = t & 63, fr = l & 15, fb = l >> 4;
    int arl = wr * 16 + fr, brl = wc * 16 + fr, koff = fb * 8;

    {
        float2 z2 = {0.f, 0.f};
        float2 pa = okA ? *(const float2*)(arow + skq) : z2;
        float2 pb = okB ? *(const float2*)(brow + skq) : z2;
        As[0][srow][skq] = f2bf(pa.x); As[0][srow][skq + 1] = f2bf(pa.y);
        Bs[0][srow][skq] = f2bf(pb.x); Bs[0][srow][skq + 1] = f2bf(pb.y);
    }
    __syncthreads();

    f32x4 acc = {0.f, 0.f, 0.f, 0.f};
    int nsteps = D >> 5;               // 32
    for (int step = 0; step < nsteps; step++) {
        int cur = step & 1;
        float2 pa, pb;
        if (step < nsteps - 1) {
            int k0n = (step + 1) * 32;
            float2 z2 = {0.f, 0.f};
            pa = okA ? *(const float2*)(arow + k0n + skq) : z2;
            pb = okB ? *(const float2*)(brow + k0n + skq) : z2;
        }
        short8v af = *reinterpret_cast<const short8v*>(&As[cur][arl][koff]);
        short8v bf = *reinterpret_cast<const short8v*>(&Bs[cur][brl][koff]);
        acc = __builtin_amdgcn_mfma_f32_16x16x32_bf16(af, bf, acc, 0, 0, 0);
        if (step < nsteps - 1) {
            int nb = cur ^ 1;
            As[nb][srow][skq] = f2bf(pa.x); As[nb][srow][skq + 1] = f2bf(pa.y);
            Bs[nb][srow][skq] = f2bf(pb.x); Bs[nb][srow][skq + 1] = f2bf(pb.y);
        }
        __syncthreads();
    }

#pragma unroll
    for (int r = 0; r < 4; r++)
        racc[(wr * 16 + fb * 4 + r) * 68 + wc * 16 + fr] = acc[r];
    __syncthreads();

    int r0 = t >> 4;
    int cbl = (t & 15) * 4;
    int gr = rb + r0;
    bool edge = (tj == NT - 1);
    if (gr < C) {
        float4 v4 = *reinterpret_cast<const float4*>(&racc[r0 * 68 + cbl]);
        float v[4] = {v4.x, v4.y, v4.z, v4.w};
        float* dst = S + (long)gr * C + cb + cbl;
        if (!edge) {
            *reinterpret_cast<float2*>(dst) = make_float2(v[0], v[1]);
            *reinterpret_cast<float2*>(dst + 2) = make_float2(v[2], v[3]);
        } else {
#pragma unroll
            for (int m = 0; m < 4; m++)
                if (cb + cbl + m < C) dst[m] = v[m];
        }
    }
    if (ti != tj) {
        int cc0 = cb + r0;
        if (cc0 < C) {
            float wv[4];
#pragma unroll
            for (int m = 0; m < 4; m++) wv[m] = racc[(cbl + m) * 68 + r0];
            float* dst = S + (long)cc0 * C + rb + cbl;
            *reinterpret_cast<float2*>(dst) = make_float2(wv[0], wv[1]);
            *reinterpret_cast<float2*>(dst + 2) = make_float2(wv[2], wv[3]);
        }
    }
}

// per-row: best/argmax (excl diag) of cos values + global min/max (incl diag).
__global__ void k_rowmax(const float* S, const float* norms, unsigned* minmax,
                         float* simraw, int* simcls, int C) {
    __shared__ float invn[1024];
    __shared__ float rv[256], rmn[256], rmx[256];
    __shared__ int ri[256];
    int c = blockIdx.x, t = threadIdx.x;
    for (int j = t; j < C; j += 256) invn[j] = 1.f / norms[j];
    __syncthreads();
    float inc = invn[c];
    float best = -INFINITY, lmin = INFINITY, lmax = -INFINITY;
    int bi = 0x7FFFFFFF;
    long rowo = (long)c * C;
    for (int j = t; j < C; j += 256) {
        float v = S[rowo + j] * inc * invn[j];
        lmin = fminf(lmin, v);
        lmax = fmaxf(lmax, v);
        if (j != c && v > best) { best = v; bi = j; }
    }
    rv[t] = best; ri[t] = bi; rmn[t] = lmin; rmx[t] = lmax;
    __syncthreads();
    for (int k = 128; k > 0; k >>= 1) {
        if (t < k) {
            if (rv[t + k] > rv[t] || (rv[t + k] == rv[t] && ri[t + k] < ri[t])) {
                rv[t] = rv[t + k];
                ri[t] = ri[t + k];
            }
            rmn[t] = fminf(rmn[t], rmn[t + k]);
            rmx[t] = fmaxf(rmx[t], rmx[t + k]);
        }
        __syncthreads();
    }
    if (t == 0) {
        simraw[c] = rv[0];
        simcls[c] = ri[0];
        atomicMin(&minmax[0], fenc(rmn[0]));
        atomicMax(&minmax[1], fenc(rmx[0]));
    }
}

// cpf[c] = n_c - dot(g_c,u_c)/max(|u_c|,eps) + sv_c*dot(g_c,v_c)/max(|v_c|,eps)
__global__ __launch_bounds__(256) void k_closs(const float* gsum, const float* ftab,
                                               const float* norms, const int* counts,
                                               const unsigned* minmax, const float* simraw,
                                               const int* simcls, float* cpf,
                                               int C, int D) {
    __shared__ float red[256];
    int c = blockIdx.x, t = threadIdx.x;
    int n = counts[c];
    if (n == 0) {
        if (t == 0) cpf[c] = 0.f;
        return;
    }
    int sc = simcls[c];
    float4 g4 = ((const float4*)(gsum + (long)c * D))[t];
    const float* u = ftab + (long)c * D + t * 4;
    const float* v = ftab + (long)sc * D + t * 4;
    float d1 = g4.x * u[0] + g4.y * u[1] + g4.z * u[2] + g4.w * u[3];
    float d2 = g4.x * v[0] + g4.y * v[1] + g4.z * v[2] + g4.w * v[3];
    d1 = block_sum(d1, red);
    d2 = block_sum(d2, red);
    if (t == 0) {
        float cmin = fdec(minmax[0]);
        float cmax = fdec(minmax[1]);
        float sv = (simraw[c] - cmin) / (cmax - cmin);
        float nu = fmaxf(norms[c], EPS);
        float nv = fmaxf(norms[sc], EPS);
        cpf[c] = (float)n - d1 / nu + sv * d2 / nv;
    }
}

__global__ void k_final(const float* cpf, const float* cpk, float* out, int C) {
    __shared__ float red[256];
    float a = 0.f;
    for (int i = threadIdx.x; i < C; i += 256) a += cpf[i];
    a = block_sum(a, red);
    float b = 0.f;
    for (int i = threadIdx.x; i < C; i += 256) b += cpk[i];
    b = block_sum(b, red);
    if (threadIdx.x == 0) {
        out[0] = a;
        out[1] = b;
    }
}

extern "C" void kernel_launch(void* const* d_in, const int* in_sizes, int n_in,
                              void* d_out, int out_size, void* d_ws, size_t ws_size,
                              hipStream_t stream) {
    const float* feature = (const float*)d_in[0];
    const float* logits  = (const float*)d_in[1];
    const int*   targets = (const int*)d_in[2];
    const float* finit   = (const float*)d_in[3];
    const float* linit   = (const float*)d_in[4];

    const int B = in_sizes[2];                 // 16384
    const int D = in_sizes[0] / B;             // 1024
    const int C = in_sizes[3] / D;             // 1000

    float* out = (float*)d_out;
    float* ftab = out + 2;                     // [C, D]
    float* ltab = out + 2 + (long)C * D;       // [C, C]

    const int G = 64;                          // histogram groups
    const int NT = (C + 63) / 64;              // 16 tiles per dim
    const int NTRI = NT * (NT + 1) / 2;        // 136 triangular tiles

    char* ws = (char*)d_ws;
    int*      counts   = (int*)(ws + 0);          // 4KB
    int*      offsets  = (int*)(ws + 4096);       // 4KB
    int*      idx      = (int*)(ws + 12288);      // 64KB
    float*    norms    = (float*)(ws + 77824);    // 4KB
    float*    simraw   = (float*)(ws + 81920);    // 4KB
    int*      simcls   = (int*)(ws + 86016);      // 4KB
    unsigned* minmax   = (unsigned*)(ws + 90112); // 8B
    float*    cpf      = (float*)(ws + 90368);    // 4KB
    float*    cpk      = (float*)(ws + 94464);    // 4KB
    float*    Sws      = (float*)(ws + 262144);   // C*C floats = 4MB
    float*    gsum     = (float*)(ws + 262144 + (size_t)C * C * sizeof(float)); // C*D

    float* S = Sws;                            // ws_size >= 12.25MB proven (round 12)

    // gh scratch lives in the (not-yet-written) ltab output region
    int* gh = (int*)ltab;

    k_hist<<<G, 256, 0, stream>>>(targets, gh, B);
    k_bases<<<1, 1024, 0, stream>>>(gh, counts, offsets, minmax, G, C);
    k_rank_scatter<<<G, 256, 0, stream>>>(targets, offsets, gh, idx, B);

    // single full-input pass: gathers + per-row norms/lse + cpk
    k_tables<<<2 * C, 256, 0, stream>>>(feature, finit, logits, linit,
                                        counts, offsets, idx,
                                        ftab, ltab, norms, gsum, cpk, C, D, C);

    k_gemm<<<NTRI, 1024, 0, stream>>>(ftab, S, C, D, NT);
    k_rowmax<<<C, 256, 0, stream>>>(S, norms, minmax, simraw, simcls, C);
    k_closs<<<C, 256, 0, stream>>>(gsum, ftab, norms, counts, minmax,
                                   simraw, simcls, cpf, C, D);
    k_final<<<1, 256, 0, stream>>>(cpf, cpk, out, C);
}

// Round 32
// 116.838 us; speedup vs baseline: 1.1742x; 1.0950x over previous
//
#include <hip/hip_runtime.h>
#include <hip/hip_bf16.h>
#include <math.h>

#define EPS 1e-8f

typedef __attribute__((ext_vector_type(8))) short short8v;
typedef __attribute__((ext_vector_type(4))) float f32x4;

// ---------- helpers ----------
__device__ __forceinline__ unsigned fenc(float f) {
    unsigned u = __float_as_uint(f);
    return (u & 0x80000000u) ? ~u : (u | 0x80000000u);
}
__device__ __forceinline__ float fdec(unsigned e) {
    unsigned u = (e & 0x80000000u) ? (e & 0x7FFFFFFFu) : ~e;
    return __uint_as_float(u);
}
__device__ __forceinline__ unsigned short f2bf(float f) {   // RNE f32 -> bf16
    unsigned u = __float_as_uint(f);
    u += 0x7FFFu + ((u >> 16) & 1u);
    return (unsigned short)(u >> 16);
}

// async global load: compiler cannot serialize volatile asm loads
__device__ __forceinline__ f32x4 gload4(const float* p) {
    f32x4 r;
    asm volatile("global_load_dwordx4 %0, %1, off" : "=v"(r) : "v"(p));
    return r;
}

__device__ __forceinline__ float block_sum(float v, float* red) {
    red[threadIdx.x] = v;
    __syncthreads();
    for (int k = 128; k > 0; k >>= 1) {
        if (threadIdx.x < k) red[threadIdx.x] += red[threadIdx.x + k];
        __syncthreads();
    }
    float r = red[0];
    __syncthreads();
    return r;
}
__device__ __forceinline__ float block_max(float v, float* red) {
    red[threadIdx.x] = v;
    __syncthreads();
    for (int k = 128; k > 0; k >>= 1) {
        if (threadIdx.x < k) red[threadIdx.x] = fmaxf(red[threadIdx.x], red[threadIdx.x + k]);
        __syncthreads();
    }
    float r = red[0];
    __syncthreads();
    return r;
}

__device__ __forceinline__ float wred_sum(float v) {
#pragma unroll
    for (int o = 32; o > 0; o >>= 1) v += __shfl_xor(v, o);
    return v;
}
__device__ __forceinline__ float wred_max(float v) {
#pragma unroll
    for (int o = 32; o > 0; o >>= 1) v = fmaxf(v, __shfl_xor(v, o));
    return v;
}

// ---------- kernels ----------
__global__ __launch_bounds__(256) void k_hist(const int* tgt, int* gh, int B) {
    __shared__ int lh[1024];
    int g = blockIdx.x, t = threadIdx.x;
    lh[t] = 0; lh[t + 256] = 0; lh[t + 512] = 0; lh[t + 768] = 0;
    __syncthreads();
    int i = g * 256 + t;
    if (i < B) atomicAdd(&lh[tgt[i]], 1);
    __syncthreads();
    int* dst = gh + g * 1024;
    dst[t] = lh[t]; dst[t + 256] = lh[t + 256];
    dst[t + 512] = lh[t + 512]; dst[t + 768] = lh[t + 768];
}

__global__ void k_bases(int* gh, int* counts, int* offsets, unsigned* minmax, int G, int C) {
    __shared__ int buf[1024];
    int c = threadIdx.x;
    if (c == 0) { minmax[0] = 0xFFFFFFFFu; minmax[1] = 0u; }
    int run = 0;
#pragma unroll 16
    for (int g = 0; g < G; g++) {
        int v = gh[g * 1024 + c];
        gh[g * 1024 + c] = run;
        run += v;
    }
    if (c < C) counts[c] = run;
    int v0 = (c < C) ? run : 0;
    buf[c] = v0;
    __syncthreads();
    for (int off = 1; off < 1024; off <<= 1) {
        int v = (c >= off) ? buf[c - off] : 0;
        __syncthreads();
        buf[c] += v;
        __syncthreads();
    }
    if (c < C) offsets[c] = buf[c] - v0;
}

__global__ void k_rank_scatter(const int* tgt, const int* offsets, const int* gh,
                               int* idx, int B) {
    __shared__ int lt[256];
    int g = blockIdx.x, t = threadIdx.x;
    int i = g * 256 + t;
    int my = (i < B) ? tgt[i] : -1;
    lt[t] = my;
    __syncthreads();
    if (i < B) {
        int rank = 0;
        for (int j = 0; j < t; j++) rank += (lt[j] == my);
        idx[offsets[my] + gh[g * 1024 + my] + rank] = i;
    }
}

// FUSED single-pass table build, wave-local per-row reductions (no per-batch syncs):
//  blocks [0,C): wave w handles rows r=w mod 4 of class c; whole row per wave
//    -> in-wave ||f||, accumulate sum f and sum f/|f|; one end-of-kernel combine.
//  blocks [C,2C): same for logits rows -> ltab + per-row lse + cpk.
__global__ __launch_bounds__(256) void k_tables(const float* feat, const float* finit,
                                                const float* logits, const float* linit,
                                                const int* counts, const int* offsets,
                                                const int* idx,
                                                float* ftab, float* ltab, float* norms,
                                                float* gsum, float* cpk,
                                                int C, int D, int C2) {
    __shared__ float red[256];
    __shared__ __align__(16) f32x4 combA[4][256];   // 16KB
    __shared__ __align__(16) f32x4 combG[4][256];   // 16KB
    __shared__ float lsew[4];
    int t = threadIdx.x;
    int lane = t & 63;
    int wid = t >> 6;
    if ((int)blockIdx.x < C) {
        // ---------------- feature path ----------------
        int c = blockIdx.x;
        int n = counts[c];
        if (n == 0) {
            float4 v = ((const float4*)(finit + (long)c * D))[t];
            float* dst = ftab + (long)c * D + t * 4;
            dst[0] = v.x; dst[1] = v.y; dst[2] = v.z; dst[3] = v.w;
            float ss = v.x * v.x + v.y * v.y + v.z * v.z + v.w * v.w;
            ss = block_sum(ss, red);
            if (t == 0) norms[c] = sqrtf(ss);
            return;
        }
        int o = offsets[c];
        f32x4 z = {0.f, 0.f, 0.f, 0.f};
        f32x4 aA0 = z, aA1 = z, aA2 = z, aA3 = z;
        f32x4 aG0 = z, aG1 = z, aG2 = z, aG3 = z;
        int r = wid;
        for (; r + 4 < n; r += 8) {
            int idA = idx[o + r];
            int idB = idx[o + r + 4];
            const float* pA = feat + (long)idA * D;
            const float* pB = feat + (long)idB * D;
            f32x4 u0 = gload4(pA + lane * 4);
            f32x4 u1 = gload4(pA + (lane + 64) * 4);
            f32x4 u2 = gload4(pA + (lane + 128) * 4);
            f32x4 u3 = gload4(pA + (lane + 192) * 4);
            f32x4 w0 = gload4(pB + lane * 4);
            f32x4 w1 = gload4(pB + (lane + 64) * 4);
            f32x4 w2 = gload4(pB + (lane + 128) * 4);
            f32x4 w3 = gload4(pB + (lane + 192) * 4);
            asm volatile("s_waitcnt vmcnt(0)"
                         : "+v"(u0), "+v"(u1), "+v"(u2), "+v"(u3),
                           "+v"(w0), "+v"(w1), "+v"(w2), "+v"(w3));
            __builtin_amdgcn_sched_barrier(0);
            float ssA = u0[0]*u0[0]+u0[1]*u0[1]+u0[2]*u0[2]+u0[3]*u0[3]
                      + u1[0]*u1[0]+u1[1]*u1[1]+u1[2]*u1[2]+u1[3]*u1[3]
                      + u2[0]*u2[0]+u2[1]*u2[1]+u2[2]*u2[2]+u2[3]*u2[3]
                      + u3[0]*u3[0]+u3[1]*u3[1]+u3[2]*u3[2]+u3[3]*u3[3];
            float ssB = w0[0]*w0[0]+w0[1]*w0[1]+w0[2]*w0[2]+w0[3]*w0[3]
                      + w1[0]*w1[0]+w1[1]*w1[1]+w1[2]*w1[2]+w1[3]*w1[3]
                      + w2[0]*w2[0]+w2[1]*w2[1]+w2[2]*w2[2]+w2[3]*w2[3]
                      + w3[0]*w3[0]+w3[1]*w3[1]+w3[2]*w3[2]+w3[3]*w3[3];
            ssA = wred_sum(ssA);
            ssB = wred_sum(ssB);
            float fnA = 1.f / fmaxf(sqrtf(ssA), EPS);
            float fnB = 1.f / fmaxf(sqrtf(ssB), EPS);
#pragma unroll
            for (int e = 0; e < 4; e++) {
                aA0[e] += u0[e]; aA1[e] += u1[e]; aA2[e] += u2[e]; aA3[e] += u3[e];
                aG0[e] += u0[e]*fnA; aG1[e] += u1[e]*fnA; aG2[e] += u2[e]*fnA; aG3[e] += u3[e]*fnA;
            }
#pragma unroll
            for (int e = 0; e < 4; e++) {
                aA0[e] += w0[e]; aA1[e] += w1[e]; aA2[e] += w2[e]; aA3[e] += w3[e];
                aG0[e] += w0[e]*fnB; aG1[e] += w1[e]*fnB; aG2[e] += w2[e]*fnB; aG3[e] += w3[e]*fnB;
            }
        }
        for (; r < n; r += 4) {
            int idA = idx[o + r];
            const float* pA = feat + (long)idA * D;
            f32x4 u0 = gload4(pA + lane * 4);
            f32x4 u1 = gload4(pA + (lane + 64) * 4);
            f32x4 u2 = gload4(pA + (lane + 128) * 4);
            f32x4 u3 = gload4(pA + (lane + 192) * 4);
            asm volatile("s_waitcnt vmcnt(0)"
                         : "+v"(u0), "+v"(u1), "+v"(u2), "+v"(u3));
            __builtin_amdgcn_sched_barrier(0);
            float ssA = u0[0]*u0[0]+u0[1]*u0[1]+u0[2]*u0[2]+u0[3]*u0[3]
                      + u1[0]*u1[0]+u1[1]*u1[1]+u1[2]*u1[2]+u1[3]*u1[3]
                      + u2[0]*u2[0]+u2[1]*u2[1]+u2[2]*u2[2]+u2[3]*u2[3]
                      + u3[0]*u3[0]+u3[1]*u3[1]+u3[2]*u3[2]+u3[3]*u3[3];
            ssA = wred_sum(ssA);
            float fnA = 1.f / fmaxf(sqrtf(ssA), EPS);
#pragma unroll
            for (int e = 0; e < 4; e++) {
                aA0[e] += u0[e]; aA1[e] += u1[e]; aA2[e] += u2[e]; aA3[e] += u3[e];
                aG0[e] += u0[e]*fnA; aG1[e] += u1[e]*fnA; aG2[e] += u2[e]*fnA; aG3[e] += u3[e]*fnA;
            }
        }
        // one-shot cross-wave combine (fixed order w0+w1+w2+w3)
        combA[wid][0 * 64 + lane] = aA0;
        combA[wid][1 * 64 + lane] = aA1;
        combA[wid][2 * 64 + lane] = aA2;
        combA[wid][3 * 64 + lane] = aA3;
        combG[wid][0 * 64 + lane] = aG0;
        combG[wid][1 * 64 + lane] = aG1;
        combG[wid][2 * 64 + lane] = aG2;
        combG[wid][3 * 64 + lane] = aG3;
        __syncthreads();
        f32x4 sA = combA[0][t];
        f32x4 sG = combG[0][t];
#pragma unroll
        for (int w2_ = 1; w2_ < 4; w2_++) {
#pragma unroll
            for (int e = 0; e < 4; e++) { sA[e] += combA[w2_][t][e]; sG[e] += combG[w2_][t][e]; }
        }
        float inv = 1.0f / (float)n;
        float o0 = sA[0] * inv, o1 = sA[1] * inv, o2 = sA[2] * inv, o3 = sA[3] * inv;
        float* dst = ftab + (long)c * D + t * 4;
        dst[0] = o0; dst[1] = o1; dst[2] = o2; dst[3] = o3;
        float4 gv = {sG[0], sG[1], sG[2], sG[3]};
        ((float4*)(gsum + (long)c * D))[t] = gv;
        float ss = o0 * o0 + o1 * o1 + o2 * o2 + o3 * o3;
        ss = block_sum(ss, red);
        if (t == 0) norms[c] = sqrtf(ss);
    } else {
        // ---------------- logits path ----------------
        int c = blockIdx.x - C;
        int n = counts[c];
        int nv = C2 >> 2;                           // 250
        if (n == 0) {
            for (int d = t; d < C2; d += 256) ltab[(long)c * C2 + d] = linit[(long)c * C2 + d];
            if (t == 0) cpk[c] = 0.f;
            return;
        }
        int o = offsets[c];
        bool l3ok = (lane + 192) < nv;              // lane < 58
        int s3 = l3ok ? (lane + 192) : (nv - 1);
        f32x4 z = {0.f, 0.f, 0.f, 0.f};
        f32x4 aL0 = z, aL1 = z, aL2 = z, aL3 = z;
        float lsum = 0.f;
        int r = wid;
        for (; r + 4 < n; r += 8) {
            int idA = idx[o + r];
            int idB = idx[o + r + 4];
            const float* pA = logits + (long)idA * C2;
            const float* pB = logits + (long)idB * C2;
            f32x4 u0 = gload4(pA + lane * 4);
            f32x4 u1 = gload4(pA + (lane + 64) * 4);
            f32x4 u2 = gload4(pA + (lane + 128) * 4);
            f32x4 u3 = gload4(pA + (long)s3 * 4);
            f32x4 w0 = gload4(pB + lane * 4);
            f32x4 w1 = gload4(pB + (lane + 64) * 4);
            f32x4 w2 = gload4(pB + (lane + 128) * 4);
            f32x4 w3 = gload4(pB + (long)s3 * 4);
            asm volatile("s_waitcnt vmcnt(0)"
                         : "+v"(u0), "+v"(u1), "+v"(u2), "+v"(u3),
                           "+v"(w0), "+v"(w1), "+v"(w2), "+v"(w3));
            __builtin_amdgcn_sched_barrier(0);
            float mA = fmaxf(fmaxf(fmaxf(u0[0],u0[1]),fmaxf(u0[2],u0[3])),
                      fmaxf(fmaxf(fmaxf(u1[0],u1[1]),fmaxf(u1[2],u1[3])),
                             fmaxf(fmaxf(u2[0],u2[1]),fmaxf(u2[2],u2[3]))));
            if (l3ok) mA = fmaxf(mA, fmaxf(fmaxf(u3[0],u3[1]),fmaxf(u3[2],u3[3])));
            float mB = fmaxf(fmaxf(fmaxf(w0[0],w0[1]),fmaxf(w0[2],w0[3])),
                      fmaxf(fmaxf(fmaxf(w1[0],w1[1]),fmaxf(w1[2],w1[3])),
                             fmaxf(fmaxf(w2[0],w2[1]),fmaxf(w2[2],w2[3]))));
            if (l3ok) mB = fmaxf(mB, fmaxf(fmaxf(w3[0],w3[1]),fmaxf(w3[2],w3[3])));
            mA = wred_max(mA);
            mB = wred_max(mB);
            float eA = __expf(u0[0]-mA)+__expf(u0[1]-mA)+__expf(u0[2]-mA)+__expf(u0[3]-mA)
                     + __expf(u1[0]-mA)+__expf(u1[1]-mA)+__expf(u1[2]-mA)+__expf(u1[3]-mA)
                     + __expf(u2[0]-mA)+__expf(u2[1]-mA)+__expf(u2[2]-mA)+__expf(u2[3]-mA);
            if (l3ok) eA += __expf(u3[0]-mA)+__expf(u3[1]-mA)+__expf(u3[2]-mA)+__expf(u3[3]-mA);
            float eB = __expf(w0[0]-mB)+__expf(w0[1]-mB)+__expf(w0[2]-mB)+__expf(w0[3]-mB)
                     + __expf(w1[0]-mB)+__expf(w1[1]-mB)+__expf(w1[2]-mB)+__expf(w1[3]-mB)
                     + __expf(w2[0]-mB)+__expf(w2[1]-mB)+__expf(w2[2]-mB)+__expf(w2[3]-mB);
            if (l3ok) eB += __expf(w3[0]-mB)+__expf(w3[1]-mB)+__expf(w3[2]-mB)+__expf(w3[3]-mB);
            eA = wred_sum(eA);
            eB = wred_sum(eB);
            lsum += mA + __logf(eA);
            lsum += mB + __logf(eB);
#pragma unroll
            for (int e = 0; e < 4; e++) {
                aL0[e] += u0[e]; aL1[e] += u1[e]; aL2[e] += u2[e]; aL3[e] += u3[e];
            }
#pragma unroll
            for (int e = 0; e < 4; e++) {
                aL0[e] += w0[e]; aL1[e] += w1[e]; aL2[e] += w2[e]; aL3[e] += w3[e];
            }
        }
        for (; r < n; r += 4) {
            int idA = idx[o + r];
            const float* pA = logits + (long)idA * C2;
            f32x4 u0 = gload4(pA + lane * 4);
            f32x4 u1 = gload4(pA + (lane + 64) * 4);
            f32x4 u2 = gload4(pA + (lane + 128) * 4);
            f32x4 u3 = gload4(pA + (long)s3 * 4);
            asm volatile("s_waitcnt vmcnt(0)"
                         : "+v"(u0), "+v"(u1), "+v"(u2), "+v"(u3));
            __builtin_amdgcn_sched_barrier(0);
            float mA = fmaxf(fmaxf(fmaxf(u0[0],u0[1]),fmaxf(u0[2],u0[3])),
                      fmaxf(fmaxf(fmaxf(u1[0],u1[1]),fmaxf(u1[2],u1[3])),
                             fmaxf(fmaxf(u2[0],u2[1]),fmaxf(u2[2],u2[3]))));
            if (l3ok) mA = fmaxf(mA, fmaxf(fmaxf(u3[0],u3[1]),fmaxf(u3[2],u3[3])));
            mA = wred_max(mA);
            float eA = __expf(u0[0]-mA)+__expf(u0[1]-mA)+__expf(u0[2]-mA)+__expf(u0[3]-mA)
                     + __expf(u1[0]-mA)+__expf(u1[1]-mA)+__expf(u1[2]-mA)+__expf(u1[3]-mA)
                     + __expf(u2[0]-mA)+__expf(u2[1]-mA)+__expf(u2[2]-mA)+__expf(u2[3]-mA);
            if (l3ok) eA += __expf(u3[0]-mA)+__expf(u3[1]-mA)+__expf(u3[2]-mA)+__expf(u3[3]-mA);
            eA = wred_sum(eA);
            lsum += mA + __logf(eA);
#pragma unroll
            for (int e = 0; e < 4; e++) {
                aL0[e] += u0[e]; aL1[e] += u1[e]; aL2[e] += u2[e]; aL3[e] += u3[e];
            }
        }
        // one-shot combine
        combA[wid][0 * 64 + lane] = aL0;
        combA[wid][1 * 64 + lane] = aL1;
        combA[wid][2 * 64 + lane] = aL2;
        combA[wid][3 * 64 + lane] = aL3;
        if (lane == 0) lsew[wid] = lsum;
        __syncthreads();
        f32x4 sL = combA[0][t];
#pragma unroll
        for (int w2_ = 1; w2_ < 4; w2_++)
#pragma unroll
            for (int e = 0; e < 4; e++) sL[e] += combA[w2_][t][e];
        float lsetotal = lsew[0] + lsew[1] + lsew[2] + lsew[3];
        float inv = 1.0f / (float)n;
        float r0 = sL[0] * inv, r1 = sL[1] * inv, r2 = sL[2] * inv, r3 = sL[3] * inv;
        bool tval = t < nv;
        if (tval) {
            float* dst = ltab + (long)c * C2 + t * 4;
            dst[0] = r0; dst[1] = r1; dst[2] = r2; dst[3] = r3;
        }
        float qm = tval ? fmaxf(fmaxf(r0, r1), fmaxf(r2, r3)) : -INFINITY;
        qm = block_max(qm, red);
        float em = tval ? (__expf(r0-qm)+__expf(r1-qm)+__expf(r2-qm)+__expf(r3-qm)) : 0.f;
        em = block_sum(em, red);
        if (t == 0) cpk[c] = lsetotal - (float)n * (qm + __logf(em));
    }
}

// Triangular raw-dot GEMM via bf16 MFMA: one block per upper-tri 64x64 tile.
__global__ __launch_bounds__(1024) void k_gemm(const float* A, float* S,
                                               int C, int D, int NT) {
    __shared__ __align__(16) unsigned short As[2][64][40];
    __shared__ __align__(16) unsigned short Bs[2][64][40];
    __shared__ __align__(16) float racc[64 * 68];
    int t = threadIdx.x;

    int q = blockIdx.x, ti = 0;
    while (q >= NT - ti) { q -= NT - ti; ti++; }
    int tj = ti + q;
    int rb = ti * 64, cb = tj * 64;

    int srow = t >> 4;
    int skq = (t & 15) * 2;
    int ga = rb + srow, gb = cb + srow;
    bool okA = ga < C, okB = gb < C;
    const float* arow = A + (long)ga * D;
    const float* brow = A + (long)gb * D;

    int w = t >> 6, wr = w >> 2, wc = w & 3;
    int l = t & 63, fr = l & 15, fb = l >> 4;
    int arl = wr * 16 + fr, brl = wc * 16 + fr, koff = fb * 8;

    {
        float2 z2 = {0.f, 0.f};
        float2 pa = okA ? *(const float2*)(arow + skq) : z2;
        float2 pb = okB ? *(const float2*)(brow + skq) : z2;
        As[0][srow][skq] = f2bf(pa.x); As[0][srow][skq + 1] = f2bf(pa.y);
        Bs[0][srow][skq] = f2bf(pb.x); Bs[0][srow][skq + 1] = f2bf(pb.y);
    }
    __syncthreads();

    f32x4 acc = {0.f, 0.f, 0.f, 0.f};
    int nsteps = D >> 5;               // 32
    for (int step = 0; step < nsteps; step++) {
        int cur = step & 1;
        float2 pa, pb;
        if (step < nsteps - 1) {
            int k0n = (step + 1) * 32;
            float2 z2 = {0.f, 0.f};
            pa = okA ? *(const float2*)(arow + k0n + skq) : z2;
            pb = okB ? *(const float2*)(brow + k0n + skq) : z2;
        }
        short8v af = *reinterpret_cast<const short8v*>(&As[cur][arl][koff]);
        short8v bf = *reinterpret_cast<const short8v*>(&Bs[cur][brl][koff]);
        acc = __builtin_amdgcn_mfma_f32_16x16x32_bf16(af, bf, acc, 0, 0, 0);
        if (step < nsteps - 1) {
            int nb = cur ^ 1;
            As[nb][srow][skq] = f2bf(pa.x); As[nb][srow][skq + 1] = f2bf(pa.y);
            Bs[nb][srow][skq] = f2bf(pb.x); Bs[nb][srow][skq + 1] = f2bf(pb.y);
        }
        __syncthreads();
    }

#pragma unroll
    for (int r = 0; r < 4; r++)
        racc[(wr * 16 + fb * 4 + r) * 68 + wc * 16 + fr] = acc[r];
    __syncthreads();

    int r0 = t >> 4;
    int cbl = (t & 15) * 4;
    int gr = rb + r0;
    bool edge = (tj == NT - 1);
    if (gr < C) {
        float4 v4 = *reinterpret_cast<const float4*>(&racc[r0 * 68 + cbl]);
        float v[4] = {v4.x, v4.y, v4.z, v4.w};
        float* dst = S + (long)gr * C + cb + cbl;
        if (!edge) {
            *reinterpret_cast<float2*>(dst) = make_float2(v[0], v[1]);
            *reinterpret_cast<float2*>(dst + 2) = make_float2(v[2], v[3]);
        } else {
#pragma unroll
            for (int m = 0; m < 4; m++)
                if (cb + cbl + m < C) dst[m] = v[m];
        }
    }
    if (ti != tj) {
        int cc0 = cb + r0;
        if (cc0 < C) {
            float wv[4];
#pragma unroll
            for (int m = 0; m < 4; m++) wv[m] = racc[(cbl + m) * 68 + r0];
            float* dst = S + (long)cc0 * C + rb + cbl;
            *reinterpret_cast<float2*>(dst) = make_float2(wv[0], wv[1]);
            *reinterpret_cast<float2*>(dst + 2) = make_float2(wv[2], wv[3]);
        }
    }
}

// per-row: best/argmax (excl diag) of cos values + global min/max (incl diag).
__global__ void k_rowmax(const float* S, const float* norms, unsigned* minmax,
                         float* simraw, int* simcls, int C) {
    __shared__ float invn[1024];
    __shared__ float rv[256], rmn[256], rmx[256];
    __shared__ int ri[256];
    int c = blockIdx.x, t = threadIdx.x;
    for (int j = t; j < C; j += 256) invn[j] = 1.f / norms[j];
    __syncthreads();
    float inc = invn[c];
    float best = -INFINITY, lmin = INFINITY, lmax = -INFINITY;
    int bi = 0x7FFFFFFF;
    long rowo = (long)c * C;
    for (int j = t; j < C; j += 256) {
        float v = S[rowo + j] * inc * invn[j];
        lmin = fminf(lmin, v);
        lmax = fmaxf(lmax, v);
        if (j != c && v > best) { best = v; bi = j; }
    }
    rv[t] = best; ri[t] = bi; rmn[t] = lmin; rmx[t] = lmax;
    __syncthreads();
    for (int k = 128; k > 0; k >>= 1) {
        if (t < k) {
            if (rv[t + k] > rv[t] || (rv[t + k] == rv[t] && ri[t + k] < ri[t])) {
                rv[t] = rv[t + k];
                ri[t] = ri[t + k];
            }
            rmn[t] = fminf(rmn[t], rmn[t + k]);
            rmx[t] = fmaxf(rmx[t], rmx[t + k]);
        }
        __syncthreads();
    }
    if (t == 0) {
        simraw[c] = rv[0];
        simcls[c] = ri[0];
        atomicMin(&minmax[0], fenc(rmn[0]));
        atomicMax(&minmax[1], fenc(rmx[0]));
    }
}

// cpf[c] = n_c - dot(g_c,u_c)/max(|u_c|,eps) + sv_c*dot(g_c,v_c)/max(|v_c|,eps)
__global__ __launch_bounds__(256) void k_closs(const float* gsum, const float* ftab,
                                               const float* norms, const int* counts,
                                               const unsigned* minmax, const float* simraw,
                                               const int* simcls, float* cpf,
                                               int C, int D) {
    __shared__ float red[256];
    int c = blockIdx.x, t = threadIdx.x;
    int n = counts[c];
    if (n == 0) {
        if (t == 0) cpf[c] = 0.f;
        return;
    }
    int sc = simcls[c];
    float4 g4 = ((const float4*)(gsum + (long)c * D))[t];
    const float* u = ftab + (long)c * D + t * 4;
    const float* v = ftab + (long)sc * D + t * 4;
    float d1 = g4.x * u[0] + g4.y * u[1] + g4.z * u[2] + g4.w * u[3];
    float d2 = g4.x * v[0] + g4.y * v[1] + g4.z * v[2] + g4.w * v[3];
    d1 = block_sum(d1, red);
    d2 = block_sum(d2, red);
    if (t == 0) {
        float cmin = fdec(minmax[0]);
        float cmax = fdec(minmax[1]);
        float sv = (simraw[c] - cmin) / (cmax - cmin);
        float nu = fmaxf(norms[c], EPS);
        float nv = fmaxf(norms[sc], EPS);
        cpf[c] = (float)n - d1 / nu + sv * d2 / nv;
    }
}

__global__ void k_final(const float* cpf, const float* cpk, float* out, int C) {
    __shared__ float red[256];
    float a = 0.f;
    for (int i = threadIdx.x; i < C; i += 256) a += cpf[i];
    a = block_sum(a, red);
    float b = 0.f;
    for (int i = threadIdx.x; i < C; i += 256) b += cpk[i];
    b = block_sum(b, red);
    if (threadIdx.x == 0) {
        out[0] = a;
        out[1] = b;
    }
}

extern "C" void kernel_launch(void* const* d_in, const int* in_sizes, int n_in,
                              void* d_out, int out_size, void* d_ws, size_t ws_size,
                              hipStream_t stream) {
    const float* feature = (const float*)d_in[0];
    const float* logits  = (const float*)d_in[1];
    const int*   targets = (const int*)d_in[2];
    const float* finit   = (const float*)d_in[3];
    const float* linit   = (const float*)d_in[4];

    const int B = in_sizes[2];                 // 16384
    const int D = in_sizes[0] / B;             // 1024
    const int C = in_sizes[3] / D;             // 1000

    float* out = (float*)d_out;
    float* ftab = out + 2;                     // [C, D]
    float* ltab = out + 2 + (long)C * D;       // [C, C]

    const int G = 64;                          // histogram groups
    const int NT = (C + 63) / 64;              // 16 tiles per dim
    const int NTRI = NT * (NT + 1) / 2;        // 136 triangular tiles

    char* ws = (char*)d_ws;
    int*      counts   = (int*)(ws + 0);          // 4KB
    int*      offsets  = (int*)(ws + 4096);       // 4KB
    int*      idx      = (int*)(ws + 12288);      // 64KB
    float*    norms    = (float*)(ws + 77824);    // 4KB
    float*    simraw   = (float*)(ws + 81920);    // 4KB
    int*      simcls   = (int*)(ws + 86016);      // 4KB
    unsigned* minmax   = (unsigned*)(ws + 90112); // 8B
    float*    cpf      = (float*)(ws + 90368);    // 4KB
    float*    cpk      = (float*)(ws + 94464);    // 4KB
    float*    Sws      = (float*)(ws + 262144);   // C*C floats = 4MB
    float*    gsum     = (float*)(ws + 262144 + (size_t)C * C * sizeof(float)); // C*D

    float* S = Sws;                            // ws_size >= 12.25MB proven (round 12)

    // gh scratch lives in the (not-yet-written) ltab output region
    int* gh = (int*)ltab;

    k_hist<<<G, 256, 0, stream>>>(targets, gh, B);
    k_bases<<<1, 1024, 0, stream>>>(gh, counts, offsets, minmax, G, C);
    k_rank_scatter<<<G, 256, 0, stream>>>(targets, offsets, gh, idx, B);

    // single full-input pass: gathers + per-row norms/lse + cpk (wave-local reductions)
    k_tables<<<2 * C, 256, 0, stream>>>(feature, finit, logits, linit,
                                        counts, offsets, idx,
                                        ftab, ltab, norms, gsum, cpk, C, D, C);

    k_gemm<<<NTRI, 1024, 0, stream>>>(ftab, S, C, D, NT);
    k_rowmax<<<C, 256, 0, stream>>>(S, norms, minmax, simraw, simcls, C);
    k_closs<<<C, 256, 0, stream>>>(gsum, ftab, norms, counts, minmax,
                                   simraw, simcls, cpf, C, D);
    k_final<<<1, 256, 0, stream>>>(cpf, cpk, out, C);
}

// Round 33
// 90.697 us; speedup vs baseline: 1.5126x; 1.2882x over previous
//
#include <hip/hip_runtime.h>
#include <hip/hip_bf16.h>
#include <math.h>

#define EPS 1e-8f

typedef __attribute__((ext_vector_type(8))) short short8v;
typedef __attribute__((ext_vector_type(4))) float f32x4;

// ---------- helpers ----------
__device__ __forceinline__ unsigned fenc(float f) {
    unsigned u = __float_as_uint(f);
    return (u & 0x80000000u) ? ~u : (u | 0x80000000u);
}
__device__ __forceinline__ float fdec(unsigned e) {
    unsigned u = (e & 0x80000000u) ? (e & 0x7FFFFFFFu) : ~e;
    return __uint_as_float(u);
}
__device__ __forceinline__ unsigned short f2bf(float f) {   // RNE f32 -> bf16
    unsigned u = __float_as_uint(f);
    u += 0x7FFFu + ((u >> 16) & 1u);
    return (unsigned short)(u >> 16);
}

// async global load: compiler cannot serialize volatile asm loads
__device__ __forceinline__ f32x4 gload4(const float* p) {
    f32x4 r;
    asm volatile("global_load_dwordx4 %0, %1, off" : "=v"(r) : "v"(p));
    return r;
}

__device__ __forceinline__ float block_sum(float v, float* red) {
    red[threadIdx.x] = v;
    __syncthreads();
    for (int k = 128; k > 0; k >>= 1) {
        if (threadIdx.x < k) red[threadIdx.x] += red[threadIdx.x + k];
        __syncthreads();
    }
    float r = red[0];
    __syncthreads();
    return r;
}
__device__ __forceinline__ float block_max(float v, float* red) {
    red[threadIdx.x] = v;
    __syncthreads();
    for (int k = 128; k > 0; k >>= 1) {
        if (threadIdx.x < k) red[threadIdx.x] = fmaxf(red[threadIdx.x], red[threadIdx.x + k]);
        __syncthreads();
    }
    float r = red[0];
    __syncthreads();
    return r;
}

__device__ __forceinline__ float wred_sum(float v) {
#pragma unroll
    for (int o = 32; o > 0; o >>= 1) v += __shfl_xor(v, o);
    return v;
}
__device__ __forceinline__ float wred_max(float v) {
#pragma unroll
    for (int o = 32; o > 0; o >>= 1) v = fmaxf(v, __shfl_xor(v, o));
    return v;
}

// ---------- kernels ----------
__global__ __launch_bounds__(256) void k_hist(const int* tgt, int* gh, int B) {
    __shared__ int lh[1024];
    int g = blockIdx.x, t = threadIdx.x;
    lh[t] = 0; lh[t + 256] = 0; lh[t + 512] = 0; lh[t + 768] = 0;
    __syncthreads();
    int i = g * 256 + t;
    if (i < B) atomicAdd(&lh[tgt[i]], 1);
    __syncthreads();
    int* dst = gh + g * 1024;
    dst[t] = lh[t]; dst[t + 256] = lh[t + 256];
    dst[t + 512] = lh[t + 512]; dst[t + 768] = lh[t + 768];
}

__global__ void k_bases(int* gh, int* counts, int* offsets, unsigned* minmax,
                        unsigned long long* rowbest, int G, int C) {
    __shared__ int buf[1024];
    int c = threadIdx.x;
    if (c == 0) { minmax[0] = 0xFFFFFFFFu; minmax[1] = 0u; }
    if (c < C) rowbest[c] = 0ull;
    int run = 0;
#pragma unroll 16
    for (int g = 0; g < G; g++) {
        int v = gh[g * 1024 + c];
        gh[g * 1024 + c] = run;
        run += v;
    }
    if (c < C) counts[c] = run;
    int v0 = (c < C) ? run : 0;
    buf[c] = v0;
    __syncthreads();
    for (int off = 1; off < 1024; off <<= 1) {
        int v = (c >= off) ? buf[c - off] : 0;
        __syncthreads();
        buf[c] += v;
        __syncthreads();
    }
    if (c < C) offsets[c] = buf[c] - v0;
}

__global__ void k_rank_scatter(const int* tgt, const int* offsets, const int* gh,
                               int* idx, int B) {
    __shared__ int lt[256];
    int g = blockIdx.x, t = threadIdx.x;
    int i = g * 256 + t;
    int my = (i < B) ? tgt[i] : -1;
    lt[t] = my;
    __syncthreads();
    if (i < B) {
        int rank = 0;
        for (int j = 0; j < t; j++) rank += (lt[j] == my);
        idx[offsets[my] + gh[g * 1024 + my] + rank] = i;
    }
}

// FUSED single-pass table build, wave-local per-row reductions (r32, verified).
__global__ __launch_bounds__(256) void k_tables(const float* feat, const float* finit,
                                                const float* logits, const float* linit,
                                                const int* counts, const int* offsets,
                                                const int* idx,
                                                float* ftab, float* ltab, float* norms,
                                                float* gsum, float* cpk,
                                                int C, int D, int C2) {
    __shared__ float red[256];
    __shared__ __align__(16) f32x4 combA[4][256];   // 16KB
    __shared__ __align__(16) f32x4 combG[4][256];   // 16KB
    __shared__ float lsew[4];
    int t = threadIdx.x;
    int lane = t & 63;
    int wid = t >> 6;
    if ((int)blockIdx.x < C) {
        // ---------------- feature path ----------------
        int c = blockIdx.x;
        int n = counts[c];
        if (n == 0) {
            float4 v = ((const float4*)(finit + (long)c * D))[t];
            float* dst = ftab + (long)c * D + t * 4;
            dst[0] = v.x; dst[1] = v.y; dst[2] = v.z; dst[3] = v.w;
            float ss = v.x * v.x + v.y * v.y + v.z * v.z + v.w * v.w;
            ss = block_sum(ss, red);
            if (t == 0) norms[c] = sqrtf(ss);
            return;
        }
        int o = offsets[c];
        f32x4 z = {0.f, 0.f, 0.f, 0.f};
        f32x4 aA0 = z, aA1 = z, aA2 = z, aA3 = z;
        f32x4 aG0 = z, aG1 = z, aG2 = z, aG3 = z;
        int r = wid;
        for (; r + 4 < n; r += 8) {
            int idA = idx[o + r];
            int idB = idx[o + r + 4];
            const float* pA = feat + (long)idA * D;
            const float* pB = feat + (long)idB * D;
            f32x4 u0 = gload4(pA + lane * 4);
            f32x4 u1 = gload4(pA + (lane + 64) * 4);
            f32x4 u2 = gload4(pA + (lane + 128) * 4);
            f32x4 u3 = gload4(pA + (lane + 192) * 4);
            f32x4 w0 = gload4(pB + lane * 4);
            f32x4 w1 = gload4(pB + (lane + 64) * 4);
            f32x4 w2 = gload4(pB + (lane + 128) * 4);
            f32x4 w3 = gload4(pB + (lane + 192) * 4);
            asm volatile("s_waitcnt vmcnt(0)"
                         : "+v"(u0), "+v"(u1), "+v"(u2), "+v"(u3),
                           "+v"(w0), "+v"(w1), "+v"(w2), "+v"(w3));
            __builtin_amdgcn_sched_barrier(0);
            float ssA = u0[0]*u0[0]+u0[1]*u0[1]+u0[2]*u0[2]+u0[3]*u0[3]
                      + u1[0]*u1[0]+u1[1]*u1[1]+u1[2]*u1[2]+u1[3]*u1[3]
                      + u2[0]*u2[0]+u2[1]*u2[1]+u2[2]*u2[2]+u2[3]*u2[3]
                      + u3[0]*u3[0]+u3[1]*u3[1]+u3[2]*u3[2]+u3[3]*u3[3];
            float ssB = w0[0]*w0[0]+w0[1]*w0[1]+w0[2]*w0[2]+w0[3]*w0[3]
                      + w1[0]*w1[0]+w1[1]*w1[1]+w1[2]*w1[2]+w1[3]*w1[3]
                      + w2[0]*w2[0]+w2[1]*w2[1]+w2[2]*w2[2]+w2[3]*w2[3]
                      + w3[0]*w3[0]+w3[1]*w3[1]+w3[2]*w3[2]+w3[3]*w3[3];
            ssA = wred_sum(ssA);
            ssB = wred_sum(ssB);
            float fnA = 1.f / fmaxf(sqrtf(ssA), EPS);
            float fnB = 1.f / fmaxf(sqrtf(ssB), EPS);
#pragma unroll
            for (int e = 0; e < 4; e++) {
                aA0[e] += u0[e]; aA1[e] += u1[e]; aA2[e] += u2[e]; aA3[e] += u3[e];
                aG0[e] += u0[e]*fnA; aG1[e] += u1[e]*fnA; aG2[e] += u2[e]*fnA; aG3[e] += u3[e]*fnA;
            }
#pragma unroll
            for (int e = 0; e < 4; e++) {
                aA0[e] += w0[e]; aA1[e] += w1[e]; aA2[e] += w2[e]; aA3[e] += w3[e];
                aG0[e] += w0[e]*fnB; aG1[e] += w1[e]*fnB; aG2[e] += w2[e]*fnB; aG3[e] += w3[e]*fnB;
            }
        }
        for (; r < n; r += 4) {
            int idA = idx[o + r];
            const float* pA = feat + (long)idA * D;
            f32x4 u0 = gload4(pA + lane * 4);
            f32x4 u1 = gload4(pA + (lane + 64) * 4);
            f32x4 u2 = gload4(pA + (lane + 128) * 4);
            f32x4 u3 = gload4(pA + (lane + 192) * 4);
            asm volatile("s_waitcnt vmcnt(0)"
                         : "+v"(u0), "+v"(u1), "+v"(u2), "+v"(u3));
            __builtin_amdgcn_sched_barrier(0);
            float ssA = u0[0]*u0[0]+u0[1]*u0[1]+u0[2]*u0[2]+u0[3]*u0[3]
                      + u1[0]*u1[0]+u1[1]*u1[1]+u1[2]*u1[2]+u1[3]*u1[3]
                      + u2[0]*u2[0]+u2[1]*u2[1]+u2[2]*u2[2]+u2[3]*u2[3]
                      + u3[0]*u3[0]+u3[1]*u3[1]+u3[2]*u3[2]+u3[3]*u3[3];
            ssA = wred_sum(ssA);
            float fnA = 1.f / fmaxf(sqrtf(ssA), EPS);
#pragma unroll
            for (int e = 0; e < 4; e++) {
                aA0[e] += u0[e]; aA1[e] += u1[e]; aA2[e] += u2[e]; aA3[e] += u3[e];
                aG0[e] += u0[e]*fnA; aG1[e] += u1[e]*fnA; aG2[e] += u2[e]*fnA; aG3[e] += u3[e]*fnA;
            }
        }
        combA[wid][0 * 64 + lane] = aA0;
        combA[wid][1 * 64 + lane] = aA1;
        combA[wid][2 * 64 + lane] = aA2;
        combA[wid][3 * 64 + lane] = aA3;
        combG[wid][0 * 64 + lane] = aG0;
        combG[wid][1 * 64 + lane] = aG1;
        combG[wid][2 * 64 + lane] = aG2;
        combG[wid][3 * 64 + lane] = aG3;
        __syncthreads();
        f32x4 sA = combA[0][t];
        f32x4 sG = combG[0][t];
#pragma unroll
        for (int w2_ = 1; w2_ < 4; w2_++) {
#pragma unroll
            for (int e = 0; e < 4; e++) { sA[e] += combA[w2_][t][e]; sG[e] += combG[w2_][t][e]; }
        }
        float inv = 1.0f / (float)n;
        float o0 = sA[0] * inv, o1 = sA[1] * inv, o2 = sA[2] * inv, o3 = sA[3] * inv;
        float* dst = ftab + (long)c * D + t * 4;
        dst[0] = o0; dst[1] = o1; dst[2] = o2; dst[3] = o3;
        float4 gv = {sG[0], sG[1], sG[2], sG[3]};
        ((float4*)(gsum + (long)c * D))[t] = gv;
        float ss = o0 * o0 + o1 * o1 + o2 * o2 + o3 * o3;
        ss = block_sum(ss, red);
        if (t == 0) norms[c] = sqrtf(ss);
    } else {
        // ---------------- logits path ----------------
        int c = blockIdx.x - C;
        int n = counts[c];
        int nv = C2 >> 2;                           // 250
        if (n == 0) {
            for (int d = t; d < C2; d += 256) ltab[(long)c * C2 + d] = linit[(long)c * C2 + d];
            if (t == 0) cpk[c] = 0.f;
            return;
        }
        int o = offsets[c];
        bool l3ok = (lane + 192) < nv;              // lane < 58
        int s3 = l3ok ? (lane + 192) : (nv - 1);
        f32x4 z = {0.f, 0.f, 0.f, 0.f};
        f32x4 aL0 = z, aL1 = z, aL2 = z, aL3 = z;
        float lsum = 0.f;
        int r = wid;
        for (; r + 4 < n; r += 8) {
            int idA = idx[o + r];
            int idB = idx[o + r + 4];
            const float* pA = logits + (long)idA * C2;
            const float* pB = logits + (long)idB * C2;
            f32x4 u0 = gload4(pA + lane * 4);
            f32x4 u1 = gload4(pA + (lane + 64) * 4);
            f32x4 u2 = gload4(pA + (lane + 128) * 4);
            f32x4 u3 = gload4(pA + (long)s3 * 4);
            f32x4 w0 = gload4(pB + lane * 4);
            f32x4 w1 = gload4(pB + (lane + 64) * 4);
            f32x4 w2 = gload4(pB + (lane + 128) * 4);
            f32x4 w3 = gload4(pB + (long)s3 * 4);
            asm volatile("s_waitcnt vmcnt(0)"
                         : "+v"(u0), "+v"(u1), "+v"(u2), "+v"(u3),
                           "+v"(w0), "+v"(w1), "+v"(w2), "+v"(w3));
            __builtin_amdgcn_sched_barrier(0);
            float mA = fmaxf(fmaxf(fmaxf(u0[0],u0[1]),fmaxf(u0[2],u0[3])),
                      fmaxf(fmaxf(fmaxf(u1[0],u1[1]),fmaxf(u1[2],u1[3])),
                             fmaxf(fmaxf(u2[0],u2[1]),fmaxf(u2[2],u2[3]))));
            if (l3ok) mA = fmaxf(mA, fmaxf(fmaxf(u3[0],u3[1]),fmaxf(u3[2],u3[3])));
            float mB = fmaxf(fmaxf(fmaxf(w0[0],w0[1]),fmaxf(w0[2],w0[3])),
                      fmaxf(fmaxf(fmaxf(w1[0],w1[1]),fmaxf(w1[2],w1[3])),
                             fmaxf(fmaxf(w2[0],w2[1]),fmaxf(w2[2],w2[3]))));
            if (l3ok) mB = fmaxf(mB, fmaxf(fmaxf(w3[0],w3[1]),fmaxf(w3[2],w3[3])));
            mA = wred_max(mA);
            mB = wred_max(mB);
            float eA = __expf(u0[0]-mA)+__expf(u0[1]-mA)+__expf(u0[2]-mA)+__expf(u0[3]-mA)
                     + __expf(u1[0]-mA)+__expf(u1[1]-mA)+__expf(u1[2]-mA)+__expf(u1[3]-mA)
                     + __expf(u2[0]-mA)+__expf(u2[1]-mA)+__expf(u2[2]-mA)+__expf(u2[3]-mA);
            if (l3ok) eA += __expf(u3[0]-mA)+__expf(u3[1]-mA)+__expf(u3[2]-mA)+__expf(u3[3]-mA);
            float eB = __expf(w0[0]-mB)+__expf(w0[1]-mB)+__expf(w0[2]-mB)+__expf(w0[3]-mB)
                     + __expf(w1[0]-mB)+__expf(w1[1]-mB)+__expf(w1[2]-mB)+__expf(w1[3]-mB)
                     + __expf(w2[0]-mB)+__expf(w2[1]-mB)+__expf(w2[2]-mB)+__expf(w2[3]-mB);
            if (l3ok) eB += __expf(w3[0]-mB)+__expf(w3[1]-mB)+__expf(w3[2]-mB)+__expf(w3[3]-mB);
            eA = wred_sum(eA);
            eB = wred_sum(eB);
            lsum += mA + __logf(eA);
            lsum += mB + __logf(eB);
#pragma unroll
            for (int e = 0; e < 4; e++) {
                aL0[e] += u0[e]; aL1[e] += u1[e]; aL2[e] += u2[e]; aL3[e] += u3[e];
            }
#pragma unroll
            for (int e = 0; e < 4; e++) {
                aL0[e] += w0[e]; aL1[e] += w1[e]; aL2[e] += w2[e]; aL3[e] += w3[e];
            }
        }
        for (; r < n; r += 4) {
            int idA = idx[o + r];
            const float* pA = logits + (long)idA * C2;
            f32x4 u0 = gload4(pA + lane * 4);
            f32x4 u1 = gload4(pA + (lane + 64) * 4);
            f32x4 u2 = gload4(pA + (lane + 128) * 4);
            f32x4 u3 = gload4(pA + (long)s3 * 4);
            asm volatile("s_waitcnt vmcnt(0)"
                         : "+v"(u0), "+v"(u1), "+v"(u2), "+v"(u3));
            __builtin_amdgcn_sched_barrier(0);
            float mA = fmaxf(fmaxf(fmaxf(u0[0],u0[1]),fmaxf(u0[2],u0[3])),
                      fmaxf(fmaxf(fmaxf(u1[0],u1[1]),fmaxf(u1[2],u1[3])),
                             fmaxf(fmaxf(u2[0],u2[1]),fmaxf(u2[2],u2[3]))));
            if (l3ok) mA = fmaxf(mA, fmaxf(fmaxf(u3[0],u3[1]),fmaxf(u3[2],u3[3])));
            mA = wred_max(mA);
            float eA = __expf(u0[0]-mA)+__expf(u0[1]-mA)+__expf(u0[2]-mA)+__expf(u0[3]-mA)
                     + __expf(u1[0]-mA)+__expf(u1[1]-mA)+__expf(u1[2]-mA)+__expf(u1[3]-mA)
                     + __expf(u2[0]-mA)+__expf(u2[1]-mA)+__expf(u2[2]-mA)+__expf(u2[3]-mA);
            if (l3ok) eA += __expf(u3[0]-mA)+__expf(u3[1]-mA)+__expf(u3[2]-mA)+__expf(u3[3]-mA);
            eA = wred_sum(eA);
            lsum += mA + __logf(eA);
#pragma unroll
            for (int e = 0; e < 4; e++) {
                aL0[e] += u0[e]; aL1[e] += u1[e]; aL2[e] += u2[e]; aL3[e] += u3[e];
            }
        }
        combA[wid][0 * 64 + lane] = aL0;
        combA[wid][1 * 64 + lane] = aL1;
        combA[wid][2 * 64 + lane] = aL2;
        combA[wid][3 * 64 + lane] = aL3;
        if (lane == 0) lsew[wid] = lsum;
        __syncthreads();
        f32x4 sL = combA[0][t];
#pragma unroll
        for (int w2_ = 1; w2_ < 4; w2_++)
#pragma unroll
            for (int e = 0; e < 4; e++) sL[e] += combA[w2_][t][e];
        float lsetotal = lsew[0] + lsew[1] + lsew[2] + lsew[3];
        float inv = 1.0f / (float)n;
        float r0 = sL[0] * inv, r1 = sL[1] * inv, r2 = sL[2] * inv, r3 = sL[3] * inv;
        bool tval = t < nv;
        if (tval) {
            float* dst = ltab + (long)c * C2 + t * 4;
            dst[0] = r0; dst[1] = r1; dst[2] = r2; dst[3] = r3;
        }
        float qm = tval ? fmaxf(fmaxf(r0, r1), fmaxf(r2, r3)) : -INFINITY;
        qm = block_max(qm, red);
        float em = tval ? (__expf(r0-qm)+__expf(r1-qm)+__expf(r2-qm)+__expf(r3-qm)) : 0.f;
        em = block_sum(em, red);
        if (t == 0) cpk[c] = lsetotal - (float)n * (qm + __logf(em));
    }
}

// Triangular GEMM via bf16 MFMA, FUSED with rowmax: per-tile cos values reduced
// in-block to per-row best (packed u64 atomicMax, smallest-index tie-break) and
// global min/max (2 atomics/block). S never materialized.
__global__ __launch_bounds__(1024) void k_gemm(const float* A, const float* norms,
                                               unsigned long long* rowbest,
                                               unsigned* minmax,
                                               int C, int D, int NT) {
    __shared__ __align__(16) unsigned short As[2][64][40];
    __shared__ __align__(16) unsigned short Bs[2][64][40];
    __shared__ __align__(16) float racc[64 * 68];
    __shared__ float invr[64], invc[64];
    __shared__ float rmnS[1024], rmxS[1024];
    int t = threadIdx.x;

    int q = blockIdx.x, ti = 0;
    while (q >= NT - ti) { q -= NT - ti; ti++; }
    int tj = ti + q;
    int rb = ti * 64, cb = tj * 64;

    int srow = t >> 4;
    int skq = (t & 15) * 2;
    int ga = rb + srow, gb = cb + srow;
    bool okA = ga < C, okB = gb < C;
    const float* arow = A + (long)ga * D;
    const float* brow = A + (long)gb * D;

    int w = t >> 6, wr = w >> 2, wc = w & 3;
    int l = t & 63, fr = l & 15, fb = l >> 4;
    int arl = wr * 16 + fr, brl = wc * 16 + fr, koff = fb * 8;

    {
        float2 z2 = {0.f, 0.f};
        float2 pa = okA ? *(const float2*)(arow + skq) : z2;
        float2 pb = okB ? *(const float2*)(brow + skq) : z2;
        As[0][srow][skq] = f2bf(pa.x); As[0][srow][skq + 1] = f2bf(pa.y);
        Bs[0][srow][skq] = f2bf(pb.x); Bs[0][srow][skq + 1] = f2bf(pb.y);
    }
    __syncthreads();

    f32x4 acc = {0.f, 0.f, 0.f, 0.f};
    int nsteps = D >> 5;               // 32
    for (int step = 0; step < nsteps; step++) {
        int cur = step & 1;
        float2 pa, pb;
        if (step < nsteps - 1) {
            int k0n = (step + 1) * 32;
            float2 z2 = {0.f, 0.f};
            pa = okA ? *(const float2*)(arow + k0n + skq) : z2;
            pb = okB ? *(const float2*)(brow + k0n + skq) : z2;
        }
        short8v af = *reinterpret_cast<const short8v*>(&As[cur][arl][koff]);
        short8v bf = *reinterpret_cast<const short8v*>(&Bs[cur][brl][koff]);
        acc = __builtin_amdgcn_mfma_f32_16x16x32_bf16(af, bf, acc, 0, 0, 0);
        if (step < nsteps - 1) {
            int nb = cur ^ 1;
            As[nb][srow][skq] = f2bf(pa.x); As[nb][srow][skq + 1] = f2bf(pa.y);
            Bs[nb][srow][skq] = f2bf(pb.x); Bs[nb][srow][skq + 1] = f2bf(pb.y);
        }
        __syncthreads();
    }

    // stage tile + inverse norms
#pragma unroll
    for (int r = 0; r < 4; r++)
        racc[(wr * 16 + fb * 4 + r) * 68 + wc * 16 + fr] = acc[r];
    if (t < 64) invr[t] = (rb + t < C) ? 1.f / norms[rb + t] : 0.f;
    else if (t < 128) invc[t - 64] = (cb + t - 64 < C) ? 1.f / norms[cb + t - 64] : 0.f;
    __syncthreads();

    // per-row (16 threads/row): cos values, min/max, argmax excl diag
    int r0 = t >> 4;
    int c4 = (t & 15) * 4;
    int gr = rb + r0;
    float lmin = INFINITY, lmax = -INFINITY;
    float best = -INFINITY;
    unsigned bidx = 0xFFFFFFFFu;
    if (gr < C) {
        float ir = invr[r0];
#pragma unroll
        for (int m = 0; m < 4; m++) {
            int gc = cb + c4 + m;
            if (gc < C) {
                float v = racc[r0 * 68 + c4 + m] * ir * invc[c4 + m];
                lmin = fminf(lmin, v);
                lmax = fmaxf(lmax, v);
                if (gc != gr && v > best) { best = v; bidx = (unsigned)gc; }
            }
        }
    }
#pragma unroll
    for (int o = 1; o < 16; o <<= 1) {
        float ob = __shfl_xor(best, o);
        unsigned oi = (unsigned)__shfl_xor((int)bidx, o);
        float omn = __shfl_xor(lmin, o);
        float omx = __shfl_xor(lmax, o);
        if (ob > best || (ob == best && oi < bidx)) { best = ob; bidx = oi; }
        lmin = fminf(lmin, omn);
        lmax = fmaxf(lmax, omx);
    }
    if ((t & 15) == 0 && gr < C && best > -INFINITY) {
        unsigned long long pk = ((unsigned long long)fenc(best) << 32) | (0xFFFFFFFFu - bidx);
        atomicMax(&rowbest[gr], pk);
    }

    // mirror argmax for off-diag tiles (values identical; min/max unaffected)
    if (ti != tj) {
        int mr = t >> 4;              // col in tile = mirrored row
        int gc = cb + mr;
        float best2 = -INFINITY;
        unsigned bidx2 = 0xFFFFFFFFu;
        if (gc < C) {
            float ic = invc[mr];
#pragma unroll
            for (int m = 0; m < 4; m++) {
                int j = c4 + m;       // row in tile; rb+j always < C for ti<tj
                float v = racc[j * 68 + mr] * ic * invr[j];
                if (v > best2) { best2 = v; bidx2 = (unsigned)(rb + j); }
            }
        }
#pragma unroll
        for (int o = 1; o < 16; o <<= 1) {
            float ob = __shfl_xor(best2, o);
            unsigned oi = (unsigned)__shfl_xor((int)bidx2, o);
            if (ob > best2 || (ob == best2 && oi < bidx2)) { best2 = ob; bidx2 = oi; }
        }
        if ((t & 15) == 0 && gc < C && best2 > -INFINITY) {
            unsigned long long pk = ((unsigned long long)fenc(best2) << 32) | (0xFFFFFFFFu - bidx2);
            atomicMax(&rowbest[gc], pk);
        }
    }

    // block min/max -> global
    rmnS[t] = lmin;
    rmxS[t] = lmax;
    __syncthreads();
    for (int k = 512; k > 0; k >>= 1) {
        if (t < k) {
            rmnS[t] = fminf(rmnS[t], rmnS[t + k]);
            rmxS[t] = fmaxf(rmxS[t], rmxS[t + k]);
        }
        __syncthreads();
    }
    if (t == 0) {
        atomicMin(&minmax[0], fenc(rmnS[0]));
        atomicMax(&minmax[1], fenc(rmxS[0]));
    }
}

// cpf[c] = n_c - dot(g_c,u_c)/max(|u_c|,eps) + sv_c*dot(g_c,v_c)/max(|v_c|,eps)
__global__ __launch_bounds__(256) void k_closs(const float* gsum, const float* ftab,
                                               const float* norms, const int* counts,
                                               const unsigned* minmax,
                                               const unsigned long long* rowbest,
                                               float* cpf, int C, int D) {
    __shared__ float red[256];
    int c = blockIdx.x, t = threadIdx.x;
    int n = counts[c];
    if (n == 0) {
        if (t == 0) cpf[c] = 0.f;
        return;
    }
    unsigned long long pk = rowbest[c];
    float bv = fdec((unsigned)(pk >> 32));
    int sc = (int)(0xFFFFFFFFu - (unsigned)(pk & 0xFFFFFFFFu));
    float4 g4 = ((const float4*)(gsum + (long)c * D))[t];
    const float* u = ftab + (long)c * D + t * 4;
    const float* v = ftab + (long)sc * D + t * 4;
    float d1 = g4.x * u[0] + g4.y * u[1] + g4.z * u[2] + g4.w * u[3];
    float d2 = g4.x * v[0] + g4.y * v[1] + g4.z * v[2] + g4.w * v[3];
    d1 = block_sum(d1, red);
    d2 = block_sum(d2, red);
    if (t == 0) {
        float cmin = fdec(minmax[0]);
        float cmax = fdec(minmax[1]);
        float sv = (bv - cmin) / (cmax - cmin);
        float nu = fmaxf(norms[c], EPS);
        float nv = fmaxf(norms[sc], EPS);
        cpf[c] = (float)n - d1 / nu + sv * d2 / nv;
    }
}

__global__ void k_final(const float* cpf, const float* cpk, float* out, int C) {
    __shared__ float red[256];
    float a = 0.f;
    for (int i = threadIdx.x; i < C; i += 256) a += cpf[i];
    a = block_sum(a, red);
    float b = 0.f;
    for (int i = threadIdx.x; i < C; i += 256) b += cpk[i];
    b = block_sum(b, red);
    if (threadIdx.x == 0) {
        out[0] = a;
        out[1] = b;
    }
}

extern "C" void kernel_launch(void* const* d_in, const int* in_sizes, int n_in,
                              void* d_out, int out_size, void* d_ws, size_t ws_size,
                              hipStream_t stream) {
    const float* feature = (const float*)d_in[0];
    const float* logits  = (const float*)d_in[1];
    const int*   targets = (const int*)d_in[2];
    const float* finit   = (const float*)d_in[3];
    const float* linit   = (const float*)d_in[4];

    const int B = in_sizes[2];                 // 16384
    const int D = in_sizes[0] / B;             // 1024
    const int C = in_sizes[3] / D;             // 1000

    float* out = (float*)d_out;
    float* ftab = out + 2;                     // [C, D]
    float* ltab = out + 2 + (long)C * D;       // [C, C]

    const int G = 64;                          // histogram groups
    const int NT = (C + 63) / 64;              // 16 tiles per dim
    const int NTRI = NT * (NT + 1) / 2;        // 136 triangular tiles

    char* ws = (char*)d_ws;
    int*      counts   = (int*)(ws + 0);          // 4KB
    int*      offsets  = (int*)(ws + 4096);       // 4KB
    int*      idx      = (int*)(ws + 12288);      // 64KB
    float*    norms    = (float*)(ws + 77824);    // 4KB
    unsigned* minmax   = (unsigned*)(ws + 90112); // 8B
    float*    cpf      = (float*)(ws + 90368);    // 4KB
    float*    cpk      = (float*)(ws + 94464);    // 4KB
    unsigned long long* rowbest = (unsigned long long*)(ws + 98560); // 8KB
    float*    gsum     = (float*)(ws + 262144);   // C*D floats = 4.1MB

    // gh scratch lives in the (not-yet-written) ltab output region
    int* gh = (int*)ltab;

    k_hist<<<G, 256, 0, stream>>>(targets, gh, B);
    k_bases<<<1, 1024, 0, stream>>>(gh, counts, offsets, minmax, rowbest, G, C);
    k_rank_scatter<<<G, 256, 0, stream>>>(targets, offsets, gh, idx, B);

    // single full-input pass: gathers + per-row norms/lse + cpk (wave-local reductions)
    k_tables<<<2 * C, 256, 0, stream>>>(feature, finit, logits, linit,
                                        counts, offsets, idx,
                                        ftab, ltab, norms, gsum, cpk, C, D, C);

    // GEMM fused with rowmax: per-row best + global min/max, no S materialization
    k_gemm<<<NTRI, 1024, 0, stream>>>(ftab, norms, rowbest, minmax, C, D, NT);
    k_closs<<<C, 256, 0, stream>>>(gsum, ftab, norms, counts, minmax,
                                   rowbest, cpf, C, D);
    k_final<<<1, 256, 0, stream>>>(cpf, cpk, out, C);
}